// Round 10
// baseline (1081.379 us; speedup 1.0000x reference)
//
#include <hip/hip_runtime.h>
#include <hip/hip_bf16.h>
#include <math.h>

#define UCNT 50000
#define ICNT 25000
#define NNODE 75000
#define DDIM 64
#define BB 4096
#define EPS_C 0.2f
#define INV_TEMP 5.0f
#define NJT (BB / 64)       // 64 j-tiles in infonce

#define NRANGE 293          // 256-node ranges
#define RB_U 196            // user-half ranges (0..195; range 195 is shared)
#define RB_I 98             // item-half ranges (195..292 -> rel 0..97)
#define QCAP 20
#define QSTR 21             // padded stride (bank spread)
#define EPB_U 2048          // user-half stripe: lambda = 2048*256/50000 ~ 10.5
#define EPB_I 1024          // item-half stripe: lambda = 1024*256/25000 ~ 10.5

typedef float floatx4 __attribute__((ext_vector_type(4)));

__device__ __forceinline__ float wave_sum(float x) {
#pragma unroll
  for (int m = 32; m >= 1; m >>= 1) x += __shfl_xor(x, m, 64);
  return x;
}

// ---------------- coarse histogram over 293 node-ranges ----------------
__global__ __launch_bounds__(256) void hist_coarse_kernel(const int* __restrict__ src,
                                                          int* __restrict__ ccnt, int ne) {
  __shared__ int h[NRANGE];
  int t = threadIdx.x;
  for (int i = t; i < NRANGE; i += 256) h[i] = 0;
  __syncthreads();
  int stride = gridDim.x * 256;
  for (int i = blockIdx.x * 256 + t; i < ne; i += stride) {
    int s = __builtin_nontemporal_load(src + i);
    atomicAdd(&h[s >> 8], 1);
  }
  __syncthreads();
  for (int i = t; i < NRANGE; i += 256)
    if (h[i]) atomicAdd(&ccnt[i], h[i]);
}

// ---------------- scan 293 range counts -> segment bases + cursors ----------------
__global__ __launch_bounds__(512) void cscan_kernel(const int* __restrict__ ccnt,
                                                    int* __restrict__ cbase,
                                                    int* __restrict__ gcur,
                                                    int* __restrict__ row_ptr, int ne) {
  int t = threadIdx.x;
  int lane = t & 63, wid = t >> 6;
  int c = (t < NRANGE) ? ccnt[t] : 0;
  int v = c;
#pragma unroll
  for (int d = 1; d < 64; d <<= 1) {
    int u = __shfl_up(v, d, 64);
    if (lane >= d) v += u;
  }
  __shared__ int ws[8], wo[8];
  if (lane == 63) ws[wid] = v;
  __syncthreads();
  if (t == 0) {
    int run = 0;
    for (int k = 0; k < 8; ++k) { wo[k] = run; run += ws[k]; }
    row_ptr[NNODE] = ne;
  }
  __syncthreads();
  if (t < NRANGE) {
    int e = v - c + wo[wid];
    cbase[t] = e;
    gcur[t] = e;
  }
}

// ---------------- partition: bin (src,dst) into contiguous per-range segments -------
// LDS queues (33 KB -> 4 blocks/CU); all binned[] writes are coalesced streams.
__global__ __launch_bounds__(256) void partition_kernel(
    const int* __restrict__ src, const int* __restrict__ dst,
    int* __restrict__ gcur, unsigned long long* __restrict__ binned, int ne, int nbu) {
  __shared__ unsigned long long q[RB_U * QSTR];
  __shared__ int qc[RB_U];
  int t = threadIdx.x;
  int eh = ne >> 1;
  bool isU = (int)blockIdx.x < nbu;
  int base = isU ? blockIdx.x * EPB_U : eh + (blockIdx.x - nbu) * EPB_I;
  int lim = min(base + (isU ? EPB_U : EPB_I), isU ? eh : ne);
  int RB = isU ? RB_U : RB_I;
  int goff = isU ? 0 : 195;
  for (int i = t; i < RB; i += 256) qc[i] = 0;
  __syncthreads();
  for (int i = base + t; i < lim; i += 256) {
    int s = __builtin_nontemporal_load(src + i);
    int d = __builtin_nontemporal_load(dst + i);
    int rb = (s >> 8) - goff;
    unsigned long long pk = ((unsigned long long)(unsigned)s << 32) | (unsigned)d;
    int pos = atomicAdd(&qc[rb], 1);
    if (pos < QCAP) q[rb * QSTR + pos] = pk;
    else { int g = atomicAdd(&gcur[rb + goff], 1); binned[g] = pk; }  // rare overflow
  }
  __syncthreads();
  int lane = t & 63, w = t >> 6;
  for (int b = w; b < RB; b += 4) {
    int cnt = min(qc[b], QCAP);
    if (cnt == 0) continue;
    int gb;
    if (lane == 0) gb = atomicAdd(&gcur[b + goff], cnt);
    gb = __shfl(gb, 0, 64);
    for (int j = lane; j < cnt; j += 64) binned[gb + j] = q[b * QSTR + j];
  }
}

// ---------------- place: one block per range -> row_ptr, counts, csr (private region)
__global__ __launch_bounds__(256) void place_kernel(
    const unsigned long long* __restrict__ binned, const int* __restrict__ cbase,
    int* __restrict__ row_ptr, int* __restrict__ counts,
    int* __restrict__ csr_dst, int ne) {
  __shared__ int cnt[256], cur[256], ws[4], wo[4];
  int t = threadIdx.x;
  int b = blockIdx.x;
  int r0 = b << 8;
  int seg0 = cbase[b];
  int seg1 = (b == NRANGE - 1) ? ne : cbase[b + 1];
  cnt[t] = 0;
  __syncthreads();
  for (int j = seg0 + t; j < seg1; j += 256)
    atomicAdd(&cnt[(int)(binned[j] >> 32) & 255], 1);
  __syncthreads();
  int c = cnt[t];
  int lane = t & 63, wid = t >> 6;
  int v = c;
#pragma unroll
  for (int d = 1; d < 64; d <<= 1) {
    int u = __shfl_up(v, d, 64);
    if (lane >= d) v += u;
  }
  if (lane == 63) ws[wid] = v;
  __syncthreads();
  if (t == 0) {
    int run = 0;
    for (int k = 0; k < 4; ++k) { wo[k] = run; run += ws[k]; }
  }
  __syncthreads();
  int excl = v - c + wo[wid];
  if (r0 + t < NNODE) {
    row_ptr[r0 + t] = seg0 + excl;
    counts[r0 + t] = c;
  }
  cur[t] = excl;
  __syncthreads();
  for (int j = seg0 + t; j < seg1; j += 256) {
    unsigned long long e = binned[j];
    int off = atomicAdd(&cur[(int)(e >> 32) & 255], 1);
    csr_dst[seg0 + off] = (int)(unsigned)e;
  }
}

// ---------------- prescale: y_init[n] = table[n] * rsqrt(max(deg,1)) ----------------
__global__ __launch_bounds__(256) void prescale_kernel(const float* __restrict__ ut,
                                                       const float* __restrict__ it,
                                                       const int* __restrict__ counts,
                                                       float* __restrict__ y) {
  int idx = blockIdx.x * 256 + threadIdx.x;   // one float4 per thread
  if (idx >= NNODE * 16) return;
  int n = idx >> 4;
  float sc = rsqrtf(fmaxf((float)counts[n], 1.f));
  const float* srcp = (n < UCNT) ? (ut + (size_t)n * DDIM)
                                 : (it + (size_t)(n - UCNT) * DDIM);
  float4 v = *(const float4*)(srcp + (idx & 15) * 4);
  v.x *= sc; v.y *= sc; v.z *= sc; v.w *= sc;
  *(float4*)((float*)y + (size_t)idx * 4) = v;
}

// ---------------- SpMM (gather-sum of prescaled rows) + noise ----------------
__global__ __launch_bounds__(256) void spmm_kernel(const float* __restrict__ y_in,
                                                   const int* __restrict__ row_ptr,
                                                   const int* __restrict__ csr_dst,
                                                   const int* __restrict__ counts,
                                                   const float* __restrict__ noise,
                                                   float* __restrict__ y_out) {
  int wave = blockIdx.x * 4 + (threadIdx.x >> 6);
  int lane = threadIdx.x & 63;
  if (wave >= NNODE) return;
  int r = wave;
  int beg = row_ptr[r], endp = row_ptr[r + 1];
  int g = lane >> 4, l16 = lane & 15;
  float4 acc = {0.f, 0.f, 0.f, 0.f};
  for (int e0 = beg; e0 < endp; e0 += 64) {
    int e = e0 + lane;
    int d = (e < endp) ? __builtin_nontemporal_load(csr_dst + e) : 0;
    int cnt = min(64, endp - e0);
    for (int j = 0; j < cnt; j += 4) {
      int dj = __shfl(d, j + g, 64);
      if (j + g < cnt) {    // group-uniform branch
        float4 xv = *(const float4*)(y_in + (size_t)dj * DDIM + l16 * 4);
        acc.x += xv.x; acc.y += xv.y; acc.z += xv.z; acc.w += xv.w;
      }
    }
  }
#pragma unroll
  for (int m = 16; m <= 32; m <<= 1) {
    acc.x += __shfl_xor(acc.x, m, 64);
    acc.y += __shfl_xor(acc.y, m, 64);
    acc.z += __shfl_xor(acc.z, m, 64);
    acc.w += __shfl_xor(acc.w, m, 64);
  }
  float sc = rsqrtf(fmaxf((float)counts[r], 1.f));
  acc.x *= sc; acc.y *= sc; acc.z *= sc; acc.w *= sc;   // x (pre-noise)
  floatx4 nfv = __builtin_nontemporal_load(
      (const floatx4*)(noise + (size_t)r * DDIM + l16 * 4));
  float4 nf = {nfv.x, nfv.y, nfv.z, nfv.w};
  float ss = nf.x * nf.x + nf.y * nf.y + nf.z * nf.z + nf.w * nf.w;
#pragma unroll
  for (int m = 1; m <= 8; m <<= 1) ss += __shfl_xor(ss, m, 64);  // 16-lane group = row
  float inv = EPS_C / fmaxf(sqrtf(ss), 1e-12f);
  float4 o;
  o.x = acc.x + ((acc.x > 0.f) ? 1.f : ((acc.x < 0.f) ? -1.f : 0.f)) * nf.x * inv;
  o.y = acc.y + ((acc.y > 0.f) ? 1.f : ((acc.y < 0.f) ? -1.f : 0.f)) * nf.y * inv;
  o.z = acc.z + ((acc.z > 0.f) ? 1.f : ((acc.z < 0.f) ? -1.f : 0.f)) * nf.z * inv;
  o.w = acc.w + ((acc.w > 0.f) ? 1.f : ((acc.w < 0.f) ? -1.f : 0.f)) * nf.w * inv;
  o.x *= sc; o.y *= sc; o.z *= sc; o.w *= sc;           // store y = x * sc
  if (g == 0) *(float4*)(y_out + (size_t)r * DDIM + l16 * 4) = o;
}

// ---------------- batch gather: BPR, reg, normalized InfoNCE inputs ----------------
__global__ __launch_bounds__(256) void batch_kernel(
    const float* __restrict__ yb0, const float* __restrict__ yb1, const float* __restrict__ yb2,
    const float* __restrict__ ut, const float* __restrict__ it,
    const int* __restrict__ counts,
    const int* __restrict__ user, const int* __restrict__ pos, const int* __restrict__ neg,
    float* __restrict__ z1u, float* __restrict__ z2u,
    float* __restrict__ z1i, float* __restrict__ z2i,
    float* __restrict__ pos_u, float* __restrict__ pos_i,
    float* __restrict__ sp_arr, float* __restrict__ rr_arr) {
  int wave = blockIdx.x * (blockDim.x >> 6) + (threadIdx.x >> 6);
  int lane = threadIdx.x & 63;
  if (wave >= BB) return;
  int b = wave;
  int iu = user[b], ip = pos[b], ing = neg[b];
  float s_u = sqrtf(fmaxf((float)counts[iu], 1.f));
  float s_p = sqrtf(fmaxf((float)counts[UCNT + ip], 1.f));
  float s_n = sqrtf(fmaxf((float)counts[UCNT + ing], 1.f));
  size_t ru = (size_t)iu * DDIM + lane;
  size_t rp = (size_t)(UCNT + ip) * DDIM + lane;
  size_t rn = (size_t)(UCNT + ing) * DDIM + lane;
  float cu = yb0[ru] * s_u;        // x_cl user row
  float ci = yb0[rp] * s_p;        // x_cl positive-item row
  float ue = (cu + (yb1[ru] + yb2[ru]) * s_u) * (1.f / 3.f);
  float pe = (ci + (yb1[rp] + yb2[rp]) * s_p) * (1.f / 3.f);
  float ne = (yb0[rn] + yb1[rn] + yb2[rn]) * s_n * (1.f / 3.f);

  float ps = wave_sum(ue * pe);
  float ns = wave_sum(ue * ne);
  float x = ns - ps;
  float sp = fmaxf(x, 0.f) + log1pf(expf(-fabsf(x)));

  float eu = ut[(size_t)iu * DDIM + lane];
  float ep = it[(size_t)ip * DDIM + lane];
  float en = it[(size_t)ing * DDIM + lane];
  float rr = wave_sum(eu * eu + ep * ep + en * en);
  if (lane == 0) { sp_arr[b] = sp; rr_arr[b] = rr; }

  float n1 = fmaxf(sqrtf(wave_sum(cu * cu)), 1e-12f);
  float n2 = fmaxf(sqrtf(wave_sum(ue * ue)), 1e-12f);
  float d12 = wave_sum(cu * ue);
  z1u[(size_t)b * DDIM + lane] = cu / n1;
  z2u[(size_t)b * DDIM + lane] = ue / n2;
  if (lane == 0) pos_u[b] = d12 / (n1 * n2) * INV_TEMP;

  float m1 = fmaxf(sqrtf(wave_sum(ci * ci)), 1e-12f);
  float m2 = fmaxf(sqrtf(wave_sum(pe * pe)), 1e-12f);
  float e12 = wave_sum(ci * pe);
  z1i[(size_t)b * DDIM + lane] = ci / m1;
  z2i[(size_t)b * DDIM + lane] = pe / m2;
  if (lane == 0) pos_i[b] = e12 / (m1 * m2) * INV_TEMP;
}

// ---------------- InfoNCE similarity tile: partial per (jtile,row), NO atomics --------
__global__ __launch_bounds__(256) void infonce_kernel(const float* __restrict__ Z1,
                                                      const float* __restrict__ Z2,
                                                      float* __restrict__ rowpart) {
  __shared__ float S1[64][65];
  __shared__ float S2[64][65];
  __shared__ float red[64][17];
  int t = threadIdx.x;
  int i0 = blockIdx.y * 64, j0 = blockIdx.x * 64;
#pragma unroll
  for (int rep = 0; rep < 4; ++rep) {
    int vlin = rep * 256 + t;       // float4 index in 64x16
    int row = vlin >> 4;
    int c4 = (vlin & 15) * 4;
    float4 a = *(const float4*)(Z1 + (size_t)(i0 + row) * DDIM + c4);
    S1[c4 + 0][row] = a.x; S1[c4 + 1][row] = a.y; S1[c4 + 2][row] = a.z; S1[c4 + 3][row] = a.w;
    float4 b = *(const float4*)(Z2 + (size_t)(j0 + row) * DDIM + c4);
    S2[c4 + 0][row] = b.x; S2[c4 + 1][row] = b.y; S2[c4 + 2][row] = b.z; S2[c4 + 3][row] = b.w;
  }
  __syncthreads();
  int ti = (t & 15) * 4;
  int tj = (t >> 4) * 4;
  float acc[4][4] = {};
  for (int k = 0; k < 64; ++k) {
    float4 av = *(const float4*)&S1[k][ti];
    float4 bv = *(const float4*)&S2[k][tj];
    float a[4] = {av.x, av.y, av.z, av.w};
    float b[4] = {bv.x, bv.y, bv.z, bv.w};
#pragma unroll
    for (int r = 0; r < 4; ++r)
#pragma unroll
      for (int c = 0; c < 4; ++c) acc[r][c] += a[r] * b[c];
  }
  int q = t >> 4;
#pragma unroll
  for (int r = 0; r < 4; ++r) {
    float s = __expf(acc[r][0] * INV_TEMP) + __expf(acc[r][1] * INV_TEMP) +
              __expf(acc[r][2] * INV_TEMP) + __expf(acc[r][3] * INV_TEMP);
    red[ti + r][q] = s;
  }
  __syncthreads();
  if (t < 64) {
    float tot = 0.f;
#pragma unroll
    for (int q2 = 0; q2 < 16; ++q2) tot += red[t][q2];
    rowpart[(size_t)blockIdx.x * BB + i0 + t] = tot;   // coalesced, no atomic
  }
}

// ---------------- reduce 64 partials per row into rowsum ----------------
__global__ __launch_bounds__(256) void reduce_kernel(const float* __restrict__ rowpart_u,
                                                     const float* __restrict__ rowpart_i,
                                                     float* __restrict__ rowsum_u,
                                                     float* __restrict__ rowsum_i) {
  int i = blockIdx.x * 256 + threadIdx.x;   // row index
  const float* src = blockIdx.y ? rowpart_i : rowpart_u;
  float s = 0.f;
#pragma unroll 8
  for (int jb = 0; jb < NJT; ++jb) s += __builtin_nontemporal_load(src + (size_t)jb * BB + i);
  if (blockIdx.y) rowsum_i[i] = s; else rowsum_u[i] = s;
}

// ---------------- finalize ----------------
__global__ __launch_bounds__(256) void finalize_kernel(const float* __restrict__ rowsum_u,
                                                       const float* __restrict__ pos_u,
                                                       const float* __restrict__ rowsum_i,
                                                       const float* __restrict__ pos_i,
                                                       const float* __restrict__ sp_arr,
                                                       const float* __restrict__ rr_arr,
                                                       float* __restrict__ out) {
  int t = threadIdx.x;
  float su = 0.f, si = 0.f, sb = 0.f, sr = 0.f;
  for (int i = t; i < BB; i += 256) {
    su += logf(rowsum_u[i]) - pos_u[i];
    si += logf(rowsum_i[i]) - pos_i[i];
    sb += sp_arr[i];
    sr += rr_arr[i];
  }
  su = wave_sum(su);
  si = wave_sum(si);
  sb = wave_sum(sb);
  sr = wave_sum(sr);
  __shared__ float sh[16];
  int lane = t & 63, wid = t >> 6;
  if (lane == 0) { sh[wid] = su; sh[4 + wid] = si; sh[8 + wid] = sb; sh[12 + wid] = sr; }
  __syncthreads();
  if (t == 0) {
    float SU = sh[0] + sh[1] + sh[2] + sh[3];
    float SI = sh[4] + sh[5] + sh[6] + sh[7];
    float SB = sh[8] + sh[9] + sh[10] + sh[11];
    float SR = sh[12] + sh[13] + sh[14] + sh[15];
    out[0] = SB * (1.f / BB);
    out[1] = 1e-4f * 0.5f * SR * (1.f / BB);
    out[2] = 0.2f * ((SU + SI) * (1.f / BB));
  }
}

extern "C" void kernel_launch(void* const* d_in, const int* in_sizes, int n_in,
                              void* d_out, int out_size, void* d_ws, size_t ws_size,
                              hipStream_t stream) {
  const float* user_table = (const float*)d_in[0];
  const float* item_table = (const float*)d_in[1];
  const float* noise      = (const float*)d_in[3];
  const int*   edge_src   = (const int*)d_in[4];
  const int*   edge_dst   = (const int*)d_in[5];
  const int*   user       = (const int*)d_in[6];
  const int*   positive   = (const int*)d_in[7];
  const int*   negative   = (const int*)d_in[8];
  const int E2 = in_sizes[2];  // 2,000,000

  char* w = (char*)d_ws;
  auto alloc = [&](size_t bytes) -> void* {
    void* p = (void*)w;
    w += (bytes + 255) & ~(size_t)255;
    return p;
  };
  int*   ccnt     = (int*)alloc((size_t)NRANGE * 4);
  int*   cbase    = (int*)alloc((size_t)NRANGE * 4);
  int*   gcur     = (int*)alloc((size_t)NRANGE * 4);
  int*   row_ptr  = (int*)alloc((size_t)(NNODE + 1) * 4);
  int*   counts   = (int*)alloc((size_t)NNODE * 4);
  int*   csr_dst  = (int*)alloc((size_t)E2 * 4);
  unsigned long long* binned = (unsigned long long*)alloc((size_t)E2 * 8);
  float* y_init   = (float*)alloc((size_t)NNODE * DDIM * 4);
  float* yb0      = (float*)alloc((size_t)NNODE * DDIM * 4);
  float* yb1      = (float*)alloc((size_t)NNODE * DDIM * 4);
  float* yb2      = (float*)alloc((size_t)NNODE * DDIM * 4);
  float* z1u      = (float*)alloc((size_t)BB * DDIM * 4);
  float* z2u      = (float*)alloc((size_t)BB * DDIM * 4);
  float* z1i      = (float*)alloc((size_t)BB * DDIM * 4);
  float* z2i      = (float*)alloc((size_t)BB * DDIM * 4);
  float* pos_u    = (float*)alloc((size_t)BB * 4);
  float* pos_i    = (float*)alloc((size_t)BB * 4);
  float* rowsum_u = (float*)alloc((size_t)BB * 4);
  float* rowsum_i = (float*)alloc((size_t)BB * 4);
  float* sp_arr   = (float*)alloc((size_t)BB * 4);
  float* rr_arr   = (float*)alloc((size_t)BB * 4);
  float* rowpart_u = (float*)alloc((size_t)NJT * BB * 4);
  float* rowpart_i = (float*)alloc((size_t)NJT * BB * 4);

  hipMemsetAsync(ccnt, 0, (size_t)NRANGE * 4, stream);
  hist_coarse_kernel<<<512, 256, 0, stream>>>(edge_src, ccnt, E2);
  cscan_kernel<<<1, 512, 0, stream>>>(ccnt, cbase, gcur, row_ptr, E2);
  const int eh = E2 >> 1;
  const int nbu = (eh + EPB_U - 1) / EPB_U;
  const int nbi = (E2 - eh + EPB_I - 1) / EPB_I;
  partition_kernel<<<nbu + nbi, 256, 0, stream>>>(edge_src, edge_dst, gcur, binned, E2, nbu);
  place_kernel<<<NRANGE, 256, 0, stream>>>(binned, cbase, row_ptr, counts, csr_dst, E2);
  prescale_kernel<<<(NNODE * 16 + 255) / 256, 256, 0, stream>>>(user_table, item_table,
                                                                counts, y_init);
  const int spmm_blocks = (NNODE + 3) / 4;  // 4 waves per 256-thread block
  spmm_kernel<<<spmm_blocks, 256, 0, stream>>>(y_init, row_ptr, csr_dst, counts,
                                               noise + (size_t)0 * NNODE * DDIM, yb0);
  spmm_kernel<<<spmm_blocks, 256, 0, stream>>>(yb0, row_ptr, csr_dst, counts,
                                               noise + (size_t)1 * NNODE * DDIM, yb1);
  spmm_kernel<<<spmm_blocks, 256, 0, stream>>>(yb1, row_ptr, csr_dst, counts,
                                               noise + (size_t)2 * NNODE * DDIM, yb2);
  batch_kernel<<<BB / 4, 256, 0, stream>>>(yb0, yb1, yb2, user_table, item_table, counts,
                                           user, positive, negative,
                                           z1u, z2u, z1i, z2i, pos_u, pos_i, sp_arr, rr_arr);
  dim3 ig(NJT, NJT);
  infonce_kernel<<<ig, 256, 0, stream>>>(z1u, z2u, rowpart_u);
  infonce_kernel<<<ig, 256, 0, stream>>>(z1i, z2i, rowpart_i);
  dim3 rg(BB / 256, 2);
  reduce_kernel<<<rg, 256, 0, stream>>>(rowpart_u, rowpart_i, rowsum_u, rowsum_i);
  finalize_kernel<<<1, 256, 0, stream>>>(rowsum_u, pos_u, rowsum_i, pos_i,
                                         sp_arr, rr_arr, (float*)d_out);
}

// Round 11
// 524.665 us; speedup vs baseline: 2.0611x; 2.0611x over previous
//
#include <hip/hip_runtime.h>
#include <hip/hip_bf16.h>
#include <math.h>

#define UCNT 50000
#define ICNT 25000
#define NNODE 75000
#define DDIM 64
#define BB 4096
#define EPS_C 0.2f
#define INV_TEMP 5.0f
#define NJT (BB / 64)       // 64 j-tiles in infonce

#define NRANGE 293          // 256-node ranges
#define RB_U 196            // user-half ranges (0..195; range 195 shared w/ items)
#define RB_I 98             // item-half ranges (195..292 -> rel 0..97)
#define GOFF_I 195
#define EPB 4096            // edges per partition block (both halves)

typedef float floatx4 __attribute__((ext_vector_type(4)));

__device__ __forceinline__ float wave_sum(float x) {
#pragma unroll
  for (int m = 32; m >= 1; m >>= 1) x += __shfl_xor(x, m, 64);
  return x;
}

// ---------------- coarse histogram over 293 node-ranges ----------------
__global__ __launch_bounds__(256) void hist_coarse_kernel(const int* __restrict__ src,
                                                          int* __restrict__ ccnt, int ne) {
  __shared__ int h[NRANGE];
  int t = threadIdx.x;
  for (int i = t; i < NRANGE; i += 256) h[i] = 0;
  __syncthreads();
  int stride = gridDim.x * 256;
  for (int i = blockIdx.x * 256 + t; i < ne; i += stride) {
    int s = __builtin_nontemporal_load(src + i);
    atomicAdd(&h[s >> 8], 1);
  }
  __syncthreads();
  for (int i = t; i < NRANGE; i += 256)
    if (h[i]) atomicAdd(&ccnt[i], h[i]);
}

// ---------------- scan 293 range counts -> segment bases ----------------
__global__ __launch_bounds__(512) void cscan_kernel(const int* __restrict__ ccnt,
                                                    int* __restrict__ cbase,
                                                    int* __restrict__ row_ptr, int ne) {
  int t = threadIdx.x;
  int lane = t & 63, wid = t >> 6;
  int c = (t < NRANGE) ? ccnt[t] : 0;
  int v = c;
#pragma unroll
  for (int d = 1; d < 64; d <<= 1) {
    int u = __shfl_up(v, d, 64);
    if (lane >= d) v += u;
  }
  __shared__ int ws[8], wo[8];
  if (lane == 63) ws[wid] = v;
  __syncthreads();
  if (t == 0) {
    int run = 0;
    for (int k = 0; k < 8; ++k) { wo[k] = run; run += ws[k]; }
    row_ptr[NNODE] = ne;
  }
  __syncthreads();
  if (t < NRANGE) cbase[t] = v - c + wo[wid];
}

// ---------------- pcount: per (stripe-block, range) histogram -> bcnt ----------------
__global__ __launch_bounds__(256) void pcount_kernel(const int* __restrict__ src,
                                                     int* __restrict__ bcnt,
                                                     int ne, int nbu, int nbp) {
  __shared__ int qc[RB_U];
  int t = threadIdx.x;
  int b = blockIdx.x;
  int eh = ne >> 1;
  bool isU = b < nbu;
  int base = isU ? b * EPB : eh + (b - nbu) * EPB;
  int lim = min(base + EPB, isU ? eh : ne);
  int RB = isU ? RB_U : RB_I;
  int goff = isU ? 0 : GOFF_I;
  for (int i = t; i < RB; i += 256) qc[i] = 0;
  __syncthreads();
  for (int i = base + t; i < lim; i += 256) {
    int s = __builtin_nontemporal_load(src + i);
    atomicAdd(&qc[(s >> 8) - goff], 1);
  }
  __syncthreads();
  for (int r = t; r < RB; r += 256) bcnt[(size_t)(r + goff) * nbp + b] = qc[r];
}

// ---------------- pscan: per range, exclusive scan over block columns ----------------
__global__ __launch_bounds__(256) void pscan_kernel(const int* __restrict__ bcnt,
                                                    const int* __restrict__ cbase,
                                                    int* __restrict__ boff, int nbp) {
  __shared__ int s0[512], s1[512];
  int r = blockIdx.x, t = threadIdx.x;
  for (int j = t; j < 512; j += 256) s0[j] = (j < nbp) ? bcnt[(size_t)r * nbp + j] : 0;
  __syncthreads();
  int* a = s0;
  int* bf = s1;
  for (int off = 1; off < 512; off <<= 1) {
    for (int j = t; j < 512; j += 256) bf[j] = a[j] + ((j >= off) ? a[j - off] : 0);
    __syncthreads();
    int* tmp = a; a = bf; bf = tmp;
  }
  int base = cbase[r];
  for (int j = t; j < nbp; j += 256)
    boff[(size_t)r * nbp + j] = base + a[j] - bcnt[(size_t)r * nbp + j];
}

// ---------------- pscatter: deterministic binning (no global atomics) ----------------
__global__ __launch_bounds__(256) void pscatter_kernel(const int* __restrict__ src,
                                                       const int* __restrict__ dst,
                                                       const int* __restrict__ boff,
                                                       unsigned long long* __restrict__ binned,
                                                       int ne, int nbu, int nbp) {
  __shared__ int qc[RB_U];
  int t = threadIdx.x;
  int b = blockIdx.x;
  int eh = ne >> 1;
  bool isU = b < nbu;
  int base = isU ? b * EPB : eh + (b - nbu) * EPB;
  int lim = min(base + EPB, isU ? eh : ne);
  int goff = isU ? 0 : GOFF_I;
  int RB = isU ? RB_U : RB_I;
  for (int i = t; i < RB; i += 256) qc[i] = 0;
  __syncthreads();
  for (int i = base + t; i < lim; i += 256) {
    int s = __builtin_nontemporal_load(src + i);
    int d = __builtin_nontemporal_load(dst + i);
    int rb = (s >> 8) - goff;
    int pos = atomicAdd(&qc[rb], 1);
    int g = boff[(size_t)(rb + goff) * nbp + b] + pos;
    binned[g] = ((unsigned long long)(unsigned)s << 32) | (unsigned)d;
  }
}

// ---------------- place: one block per range -> row_ptr, counts, csr (private region)
__global__ __launch_bounds__(256) void place_kernel(
    const unsigned long long* __restrict__ binned, const int* __restrict__ cbase,
    int* __restrict__ row_ptr, int* __restrict__ counts,
    int* __restrict__ csr_dst, int ne) {
  __shared__ int cnt[256], cur[256], ws[4], wo[4];
  int t = threadIdx.x;
  int b = blockIdx.x;
  int r0 = b << 8;
  int seg0 = cbase[b];
  int seg1 = (b == NRANGE - 1) ? ne : cbase[b + 1];
  cnt[t] = 0;
  __syncthreads();
  for (int j = seg0 + t; j < seg1; j += 256)
    atomicAdd(&cnt[(int)(binned[j] >> 32) & 255], 1);
  __syncthreads();
  int c = cnt[t];
  int lane = t & 63, wid = t >> 6;
  int v = c;
#pragma unroll
  for (int d = 1; d < 64; d <<= 1) {
    int u = __shfl_up(v, d, 64);
    if (lane >= d) v += u;
  }
  if (lane == 63) ws[wid] = v;
  __syncthreads();
  if (t == 0) {
    int run = 0;
    for (int k = 0; k < 4; ++k) { wo[k] = run; run += ws[k]; }
  }
  __syncthreads();
  int excl = v - c + wo[wid];
  if (r0 + t < NNODE) {
    row_ptr[r0 + t] = seg0 + excl;
    counts[r0 + t] = c;
  }
  cur[t] = excl;
  __syncthreads();
  for (int j = seg0 + t; j < seg1; j += 256) {
    unsigned long long e = binned[j];
    int off = atomicAdd(&cur[(int)(e >> 32) & 255], 1);
    csr_dst[seg0 + off] = (int)(unsigned)e;
  }
}

// ---------------- prescale: y_init[n] = table[n] * rsqrt(max(deg,1)) ----------------
__global__ __launch_bounds__(256) void prescale_kernel(const float* __restrict__ ut,
                                                       const float* __restrict__ it,
                                                       const int* __restrict__ counts,
                                                       float* __restrict__ y) {
  int idx = blockIdx.x * 256 + threadIdx.x;   // one float4 per thread
  if (idx >= NNODE * 16) return;
  int n = idx >> 4;
  float sc = rsqrtf(fmaxf((float)counts[n], 1.f));
  const float* srcp = (n < UCNT) ? (ut + (size_t)n * DDIM)
                                 : (it + (size_t)(n - UCNT) * DDIM);
  float4 v = *(const float4*)(srcp + (idx & 15) * 4);
  v.x *= sc; v.y *= sc; v.z *= sc; v.w *= sc;
  *(float4*)((float*)y + (size_t)idx * 4) = v;
}

// ---------------- SpMM (gather-sum of prescaled rows) + noise ----------------
__global__ __launch_bounds__(256) void spmm_kernel(const float* __restrict__ y_in,
                                                   const int* __restrict__ row_ptr,
                                                   const int* __restrict__ csr_dst,
                                                   const int* __restrict__ counts,
                                                   const float* __restrict__ noise,
                                                   float* __restrict__ y_out) {
  int wave = blockIdx.x * 4 + (threadIdx.x >> 6);
  int lane = threadIdx.x & 63;
  if (wave >= NNODE) return;
  int r = wave;
  int beg = row_ptr[r], endp = row_ptr[r + 1];
  int g = lane >> 4, l16 = lane & 15;
  float4 acc = {0.f, 0.f, 0.f, 0.f};
  for (int e0 = beg; e0 < endp; e0 += 64) {
    int e = e0 + lane;
    int d = (e < endp) ? __builtin_nontemporal_load(csr_dst + e) : 0;
    int cnt = min(64, endp - e0);
    for (int j = 0; j < cnt; j += 4) {
      int dj = __shfl(d, j + g, 64);
      if (j + g < cnt) {    // group-uniform branch
        float4 xv = *(const float4*)(y_in + (size_t)dj * DDIM + l16 * 4);
        acc.x += xv.x; acc.y += xv.y; acc.z += xv.z; acc.w += xv.w;
      }
    }
  }
#pragma unroll
  for (int m = 16; m <= 32; m <<= 1) {
    acc.x += __shfl_xor(acc.x, m, 64);
    acc.y += __shfl_xor(acc.y, m, 64);
    acc.z += __shfl_xor(acc.z, m, 64);
    acc.w += __shfl_xor(acc.w, m, 64);
  }
  float sc = rsqrtf(fmaxf((float)counts[r], 1.f));
  acc.x *= sc; acc.y *= sc; acc.z *= sc; acc.w *= sc;   // x (pre-noise)
  floatx4 nfv = __builtin_nontemporal_load(
      (const floatx4*)(noise + (size_t)r * DDIM + l16 * 4));
  float4 nf = {nfv.x, nfv.y, nfv.z, nfv.w};
  float ss = nf.x * nf.x + nf.y * nf.y + nf.z * nf.z + nf.w * nf.w;
#pragma unroll
  for (int m = 1; m <= 8; m <<= 1) ss += __shfl_xor(ss, m, 64);  // 16-lane group = row
  float inv = EPS_C / fmaxf(sqrtf(ss), 1e-12f);
  float4 o;
  o.x = acc.x + ((acc.x > 0.f) ? 1.f : ((acc.x < 0.f) ? -1.f : 0.f)) * nf.x * inv;
  o.y = acc.y + ((acc.y > 0.f) ? 1.f : ((acc.y < 0.f) ? -1.f : 0.f)) * nf.y * inv;
  o.z = acc.z + ((acc.z > 0.f) ? 1.f : ((acc.z < 0.f) ? -1.f : 0.f)) * nf.z * inv;
  o.w = acc.w + ((acc.w > 0.f) ? 1.f : ((acc.w < 0.f) ? -1.f : 0.f)) * nf.w * inv;
  o.x *= sc; o.y *= sc; o.z *= sc; o.w *= sc;           // store y = x * sc
  if (g == 0) *(float4*)(y_out + (size_t)r * DDIM + l16 * 4) = o;
}

// ---------------- batch gather: BPR, reg, normalized InfoNCE inputs ----------------
__global__ __launch_bounds__(256) void batch_kernel(
    const float* __restrict__ yb0, const float* __restrict__ yb1, const float* __restrict__ yb2,
    const float* __restrict__ ut, const float* __restrict__ it,
    const int* __restrict__ counts,
    const int* __restrict__ user, const int* __restrict__ pos, const int* __restrict__ neg,
    float* __restrict__ z1u, float* __restrict__ z2u,
    float* __restrict__ z1i, float* __restrict__ z2i,
    float* __restrict__ pos_u, float* __restrict__ pos_i,
    float* __restrict__ sp_arr, float* __restrict__ rr_arr) {
  int wave = blockIdx.x * (blockDim.x >> 6) + (threadIdx.x >> 6);
  int lane = threadIdx.x & 63;
  if (wave >= BB) return;
  int b = wave;
  int iu = user[b], ip = pos[b], ing = neg[b];
  float s_u = sqrtf(fmaxf((float)counts[iu], 1.f));
  float s_p = sqrtf(fmaxf((float)counts[UCNT + ip], 1.f));
  float s_n = sqrtf(fmaxf((float)counts[UCNT + ing], 1.f));
  size_t ru = (size_t)iu * DDIM + lane;
  size_t rp = (size_t)(UCNT + ip) * DDIM + lane;
  size_t rn = (size_t)(UCNT + ing) * DDIM + lane;
  float cu = yb0[ru] * s_u;        // x_cl user row
  float ci = yb0[rp] * s_p;        // x_cl positive-item row
  float ue = (cu + (yb1[ru] + yb2[ru]) * s_u) * (1.f / 3.f);
  float pe = (ci + (yb1[rp] + yb2[rp]) * s_p) * (1.f / 3.f);
  float ne = (yb0[rn] + yb1[rn] + yb2[rn]) * s_n * (1.f / 3.f);

  float ps = wave_sum(ue * pe);
  float ns = wave_sum(ue * ne);
  float x = ns - ps;
  float sp = fmaxf(x, 0.f) + log1pf(expf(-fabsf(x)));

  float eu = ut[(size_t)iu * DDIM + lane];
  float ep = it[(size_t)ip * DDIM + lane];
  float en = it[(size_t)ing * DDIM + lane];
  float rr = wave_sum(eu * eu + ep * ep + en * en);
  if (lane == 0) { sp_arr[b] = sp; rr_arr[b] = rr; }

  float n1 = fmaxf(sqrtf(wave_sum(cu * cu)), 1e-12f);
  float n2 = fmaxf(sqrtf(wave_sum(ue * ue)), 1e-12f);
  float d12 = wave_sum(cu * ue);
  z1u[(size_t)b * DDIM + lane] = cu / n1;
  z2u[(size_t)b * DDIM + lane] = ue / n2;
  if (lane == 0) pos_u[b] = d12 / (n1 * n2) * INV_TEMP;

  float m1 = fmaxf(sqrtf(wave_sum(ci * ci)), 1e-12f);
  float m2 = fmaxf(sqrtf(wave_sum(pe * pe)), 1e-12f);
  float e12 = wave_sum(ci * pe);
  z1i[(size_t)b * DDIM + lane] = ci / m1;
  z2i[(size_t)b * DDIM + lane] = pe / m2;
  if (lane == 0) pos_i[b] = e12 / (m1 * m2) * INV_TEMP;
}

// ---------------- InfoNCE similarity tile: partial per (jtile,row), NO atomics --------
__global__ __launch_bounds__(256) void infonce_kernel(const float* __restrict__ Z1,
                                                      const float* __restrict__ Z2,
                                                      float* __restrict__ rowpart) {
  __shared__ float S1[64][65];
  __shared__ float S2[64][65];
  __shared__ float red[64][17];
  int t = threadIdx.x;
  int i0 = blockIdx.y * 64, j0 = blockIdx.x * 64;
#pragma unroll
  for (int rep = 0; rep < 4; ++rep) {
    int vlin = rep * 256 + t;       // float4 index in 64x16
    int row = vlin >> 4;
    int c4 = (vlin & 15) * 4;
    float4 a = *(const float4*)(Z1 + (size_t)(i0 + row) * DDIM + c4);
    S1[c4 + 0][row] = a.x; S1[c4 + 1][row] = a.y; S1[c4 + 2][row] = a.z; S1[c4 + 3][row] = a.w;
    float4 b = *(const float4*)(Z2 + (size_t)(j0 + row) * DDIM + c4);
    S2[c4 + 0][row] = b.x; S2[c4 + 1][row] = b.y; S2[c4 + 2][row] = b.z; S2[c4 + 3][row] = b.w;
  }
  __syncthreads();
  int ti = (t & 15) * 4;
  int tj = (t >> 4) * 4;
  float acc[4][4] = {};
  for (int k = 0; k < 64; ++k) {
    float4 av = *(const float4*)&S1[k][ti];
    float4 bv = *(const float4*)&S2[k][tj];
    float a[4] = {av.x, av.y, av.z, av.w};
    float b[4] = {bv.x, bv.y, bv.z, bv.w};
#pragma unroll
    for (int r = 0; r < 4; ++r)
#pragma unroll
      for (int c = 0; c < 4; ++c) acc[r][c] += a[r] * b[c];
  }
  int q = t >> 4;
#pragma unroll
  for (int r = 0; r < 4; ++r) {
    float s = __expf(acc[r][0] * INV_TEMP) + __expf(acc[r][1] * INV_TEMP) +
              __expf(acc[r][2] * INV_TEMP) + __expf(acc[r][3] * INV_TEMP);
    red[ti + r][q] = s;
  }
  __syncthreads();
  if (t < 64) {
    float tot = 0.f;
#pragma unroll
    for (int q2 = 0; q2 < 16; ++q2) tot += red[t][q2];
    rowpart[(size_t)blockIdx.x * BB + i0 + t] = tot;   // coalesced, no atomic
  }
}

// ---------------- reduce 64 partials per row into rowsum ----------------
__global__ __launch_bounds__(256) void reduce_kernel(const float* __restrict__ rowpart_u,
                                                     const float* __restrict__ rowpart_i,
                                                     float* __restrict__ rowsum_u,
                                                     float* __restrict__ rowsum_i) {
  int i = blockIdx.x * 256 + threadIdx.x;   // row index
  const float* src = blockIdx.y ? rowpart_i : rowpart_u;
  float s = 0.f;
#pragma unroll 8
  for (int jb = 0; jb < NJT; ++jb) s += __builtin_nontemporal_load(src + (size_t)jb * BB + i);
  if (blockIdx.y) rowsum_i[i] = s; else rowsum_u[i] = s;
}

// ---------------- finalize ----------------
__global__ __launch_bounds__(256) void finalize_kernel(const float* __restrict__ rowsum_u,
                                                       const float* __restrict__ pos_u,
                                                       const float* __restrict__ rowsum_i,
                                                       const float* __restrict__ pos_i,
                                                       const float* __restrict__ sp_arr,
                                                       const float* __restrict__ rr_arr,
                                                       float* __restrict__ out) {
  int t = threadIdx.x;
  float su = 0.f, si = 0.f, sb = 0.f, sr = 0.f;
  for (int i = t; i < BB; i += 256) {
    su += logf(rowsum_u[i]) - pos_u[i];
    si += logf(rowsum_i[i]) - pos_i[i];
    sb += sp_arr[i];
    sr += rr_arr[i];
  }
  su = wave_sum(su);
  si = wave_sum(si);
  sb = wave_sum(sb);
  sr = wave_sum(sr);
  __shared__ float sh[16];
  int lane = t & 63, wid = t >> 6;
  if (lane == 0) { sh[wid] = su; sh[4 + wid] = si; sh[8 + wid] = sb; sh[12 + wid] = sr; }
  __syncthreads();
  if (t == 0) {
    float SU = sh[0] + sh[1] + sh[2] + sh[3];
    float SI = sh[4] + sh[5] + sh[6] + sh[7];
    float SB = sh[8] + sh[9] + sh[10] + sh[11];
    float SR = sh[12] + sh[13] + sh[14] + sh[15];
    out[0] = SB * (1.f / BB);
    out[1] = 1e-4f * 0.5f * SR * (1.f / BB);
    out[2] = 0.2f * ((SU + SI) * (1.f / BB));
  }
}

extern "C" void kernel_launch(void* const* d_in, const int* in_sizes, int n_in,
                              void* d_out, int out_size, void* d_ws, size_t ws_size,
                              hipStream_t stream) {
  const float* user_table = (const float*)d_in[0];
  const float* item_table = (const float*)d_in[1];
  const float* noise      = (const float*)d_in[3];
  const int*   edge_src   = (const int*)d_in[4];
  const int*   edge_dst   = (const int*)d_in[5];
  const int*   user       = (const int*)d_in[6];
  const int*   positive   = (const int*)d_in[7];
  const int*   negative   = (const int*)d_in[8];
  const int E2 = in_sizes[2];  // 2,000,000

  const int eh = E2 >> 1;
  const int nbu = (eh + EPB - 1) / EPB;            // 245
  const int nbi = (E2 - eh + EPB - 1) / EPB;       // 245
  const int nbp = nbu + nbi;                       // 490

  char* w = (char*)d_ws;
  auto alloc = [&](size_t bytes) -> void* {
    void* p = (void*)w;
    w += (bytes + 255) & ~(size_t)255;
    return p;
  };
  int*   ccnt     = (int*)alloc((size_t)NRANGE * 4);
  int*   cbase    = (int*)alloc((size_t)NRANGE * 4);
  int*   bcnt     = (int*)alloc((size_t)NRANGE * nbp * 4);
  int*   boff     = (int*)alloc((size_t)NRANGE * nbp * 4);
  int*   row_ptr  = (int*)alloc((size_t)(NNODE + 1) * 4);
  int*   counts   = (int*)alloc((size_t)NNODE * 4);
  int*   csr_dst  = (int*)alloc((size_t)E2 * 4);
  unsigned long long* binned = (unsigned long long*)alloc((size_t)E2 * 8);
  float* y_init   = (float*)alloc((size_t)NNODE * DDIM * 4);
  float* yb0      = (float*)alloc((size_t)NNODE * DDIM * 4);
  float* yb1      = (float*)alloc((size_t)NNODE * DDIM * 4);
  float* yb2      = (float*)alloc((size_t)NNODE * DDIM * 4);
  float* z1u      = (float*)alloc((size_t)BB * DDIM * 4);
  float* z2u      = (float*)alloc((size_t)BB * DDIM * 4);
  float* z1i      = (float*)alloc((size_t)BB * DDIM * 4);
  float* z2i      = (float*)alloc((size_t)BB * DDIM * 4);
  float* pos_u    = (float*)alloc((size_t)BB * 4);
  float* pos_i    = (float*)alloc((size_t)BB * 4);
  float* rowsum_u = (float*)alloc((size_t)BB * 4);
  float* rowsum_i = (float*)alloc((size_t)BB * 4);
  float* sp_arr   = (float*)alloc((size_t)BB * 4);
  float* rr_arr   = (float*)alloc((size_t)BB * 4);
  float* rowpart_u = (float*)alloc((size_t)NJT * BB * 4);
  float* rowpart_i = (float*)alloc((size_t)NJT * BB * 4);

  hipMemsetAsync(ccnt, 0, (size_t)NRANGE * 4, stream);
  hipMemsetAsync(bcnt, 0, (size_t)NRANGE * nbp * 4, stream);
  hist_coarse_kernel<<<512, 256, 0, stream>>>(edge_src, ccnt, E2);
  cscan_kernel<<<1, 512, 0, stream>>>(ccnt, cbase, row_ptr, E2);
  pcount_kernel<<<nbp, 256, 0, stream>>>(edge_src, bcnt, E2, nbu, nbp);
  pscan_kernel<<<NRANGE, 256, 0, stream>>>(bcnt, cbase, boff, nbp);
  pscatter_kernel<<<nbp, 256, 0, stream>>>(edge_src, edge_dst, boff, binned, E2, nbu, nbp);
  place_kernel<<<NRANGE, 256, 0, stream>>>(binned, cbase, row_ptr, counts, csr_dst, E2);
  prescale_kernel<<<(NNODE * 16 + 255) / 256, 256, 0, stream>>>(user_table, item_table,
                                                                counts, y_init);
  const int spmm_blocks = (NNODE + 3) / 4;  // 4 waves per 256-thread block
  spmm_kernel<<<spmm_blocks, 256, 0, stream>>>(y_init, row_ptr, csr_dst, counts,
                                               noise + (size_t)0 * NNODE * DDIM, yb0);
  spmm_kernel<<<spmm_blocks, 256, 0, stream>>>(yb0, row_ptr, csr_dst, counts,
                                               noise + (size_t)1 * NNODE * DDIM, yb1);
  spmm_kernel<<<spmm_blocks, 256, 0, stream>>>(yb1, row_ptr, csr_dst, counts,
                                               noise + (size_t)2 * NNODE * DDIM, yb2);
  batch_kernel<<<BB / 4, 256, 0, stream>>>(yb0, yb1, yb2, user_table, item_table, counts,
                                           user, positive, negative,
                                           z1u, z2u, z1i, z2i, pos_u, pos_i, sp_arr, rr_arr);
  dim3 ig(NJT, NJT);
  infonce_kernel<<<ig, 256, 0, stream>>>(z1u, z2u, rowpart_u);
  infonce_kernel<<<ig, 256, 0, stream>>>(z1i, z2i, rowpart_i);
  dim3 rg(BB / 256, 2);
  reduce_kernel<<<rg, 256, 0, stream>>>(rowpart_u, rowpart_i, rowsum_u, rowsum_i);
  finalize_kernel<<<1, 256, 0, stream>>>(rowsum_u, pos_u, rowsum_i, pos_i,
                                         sp_arr, rr_arr, (float*)d_out);
}

// Round 12
// 470.425 us; speedup vs baseline: 2.2987x; 1.1153x over previous
//
#include <hip/hip_runtime.h>
#include <hip/hip_bf16.h>
#include <math.h>

#define UCNT 50000
#define ICNT 25000
#define NNODE 75000
#define DDIM 64
#define BB 4096
#define EPS_C 0.2f
#define INV_TEMP 5.0f
#define NJT (BB / 64)       // 64 j-tiles in infonce

#define NRANGE 293          // 256-node ranges
#define RB_U 196            // user-half ranges (0..195; range 195 shared w/ items)
#define RB_I 98             // item-half ranges (195..292 -> rel 0..97)
#define GOFF_I 195
#define EPB 4096            // edges per partition block (both halves)

typedef float floatx4 __attribute__((ext_vector_type(4)));
typedef unsigned short ushortx8 __attribute__((ext_vector_type(8)));
typedef unsigned short ushortx4 __attribute__((ext_vector_type(4)));

__device__ __forceinline__ float wave_sum(float x) {
#pragma unroll
  for (int m = 32; m >= 1; m >>= 1) x += __shfl_xor(x, m, 64);
  return x;
}

__device__ __forceinline__ unsigned short f2bf(float f) {   // RNE
  unsigned u = __float_as_uint(f);
  u += 0x7fffu + ((u >> 16) & 1u);
  return (unsigned short)(u >> 16);
}
__device__ __forceinline__ float bf2f(unsigned short h) {
  return __uint_as_float((unsigned)h << 16);
}

// ---------------- coarse histogram over 293 node-ranges ----------------
__global__ __launch_bounds__(256) void hist_coarse_kernel(const int* __restrict__ src,
                                                          int* __restrict__ ccnt, int ne) {
  __shared__ int h[NRANGE];
  int t = threadIdx.x;
  for (int i = t; i < NRANGE; i += 256) h[i] = 0;
  __syncthreads();
  int stride = gridDim.x * 256;
  for (int i = blockIdx.x * 256 + t; i < ne; i += stride) {
    int s = __builtin_nontemporal_load(src + i);
    atomicAdd(&h[s >> 8], 1);
  }
  __syncthreads();
  for (int i = t; i < NRANGE; i += 256)
    if (h[i]) atomicAdd(&ccnt[i], h[i]);
}

// ---------------- scan 293 range counts -> segment bases ----------------
__global__ __launch_bounds__(512) void cscan_kernel(const int* __restrict__ ccnt,
                                                    int* __restrict__ cbase,
                                                    int* __restrict__ row_ptr, int ne) {
  int t = threadIdx.x;
  int lane = t & 63, wid = t >> 6;
  int c = (t < NRANGE) ? ccnt[t] : 0;
  int v = c;
#pragma unroll
  for (int d = 1; d < 64; d <<= 1) {
    int u = __shfl_up(v, d, 64);
    if (lane >= d) v += u;
  }
  __shared__ int ws[8], wo[8];
  if (lane == 63) ws[wid] = v;
  __syncthreads();
  if (t == 0) {
    int run = 0;
    for (int k = 0; k < 8; ++k) { wo[k] = run; run += ws[k]; }
    row_ptr[NNODE] = ne;
  }
  __syncthreads();
  if (t < NRANGE) cbase[t] = v - c + wo[wid];
}

// ---------------- pcount: per (stripe-block, range) histogram -> bcnt ----------------
__global__ __launch_bounds__(256) void pcount_kernel(const int* __restrict__ src,
                                                     int* __restrict__ bcnt,
                                                     int ne, int nbu, int nbp) {
  __shared__ int qc[RB_U];
  int t = threadIdx.x;
  int b = blockIdx.x;
  int eh = ne >> 1;
  bool isU = b < nbu;
  int base = isU ? b * EPB : eh + (b - nbu) * EPB;
  int lim = min(base + EPB, isU ? eh : ne);
  int RB = isU ? RB_U : RB_I;
  int goff = isU ? 0 : GOFF_I;
  for (int i = t; i < RB; i += 256) qc[i] = 0;
  __syncthreads();
  for (int i = base + t; i < lim; i += 256) {
    int s = __builtin_nontemporal_load(src + i);
    atomicAdd(&qc[(s >> 8) - goff], 1);
  }
  __syncthreads();
  for (int r = t; r < RB; r += 256) bcnt[(size_t)(r + goff) * nbp + b] = qc[r];
}

// ---------------- pscan: per range, exclusive scan over block columns ----------------
__global__ __launch_bounds__(256) void pscan_kernel(const int* __restrict__ bcnt,
                                                    const int* __restrict__ cbase,
                                                    int* __restrict__ boff, int nbp) {
  __shared__ int s0[512], s1[512];
  int r = blockIdx.x, t = threadIdx.x;
  for (int j = t; j < 512; j += 256) s0[j] = (j < nbp) ? bcnt[(size_t)r * nbp + j] : 0;
  __syncthreads();
  int* a = s0;
  int* bf = s1;
  for (int off = 1; off < 512; off <<= 1) {
    for (int j = t; j < 512; j += 256) bf[j] = a[j] + ((j >= off) ? a[j - off] : 0);
    __syncthreads();
    int* tmp = a; a = bf; bf = tmp;
  }
  int base = cbase[r];
  for (int j = t; j < nbp; j += 256)
    boff[(size_t)r * nbp + j] = base + a[j] - bcnt[(size_t)r * nbp + j];
}

// ---------------- pscatter: deterministic binning (no global atomics) ----------------
__global__ __launch_bounds__(256) void pscatter_kernel(const int* __restrict__ src,
                                                       const int* __restrict__ dst,
                                                       const int* __restrict__ boff,
                                                       unsigned long long* __restrict__ binned,
                                                       int ne, int nbu, int nbp) {
  __shared__ int qc[RB_U];
  int t = threadIdx.x;
  int b = blockIdx.x;
  int eh = ne >> 1;
  bool isU = b < nbu;
  int base = isU ? b * EPB : eh + (b - nbu) * EPB;
  int lim = min(base + EPB, isU ? eh : ne);
  int goff = isU ? 0 : GOFF_I;
  int RB = isU ? RB_U : RB_I;
  for (int i = t; i < RB; i += 256) qc[i] = 0;
  __syncthreads();
  for (int i = base + t; i < lim; i += 256) {
    int s = __builtin_nontemporal_load(src + i);
    int d = __builtin_nontemporal_load(dst + i);
    int rb = (s >> 8) - goff;
    int pos = atomicAdd(&qc[rb], 1);
    int g = boff[(size_t)(rb + goff) * nbp + b] + pos;
    binned[g] = ((unsigned long long)(unsigned)s << 32) | (unsigned)d;
  }
}

// ---------------- place: one block per range -> row_ptr, counts, csr (private region)
__global__ __launch_bounds__(256) void place_kernel(
    const unsigned long long* __restrict__ binned, const int* __restrict__ cbase,
    int* __restrict__ row_ptr, int* __restrict__ counts,
    int* __restrict__ csr_dst, int ne) {
  __shared__ int cnt[256], cur[256], ws[4], wo[4];
  int t = threadIdx.x;
  int b = blockIdx.x;
  int r0 = b << 8;
  int seg0 = cbase[b];
  int seg1 = (b == NRANGE - 1) ? ne : cbase[b + 1];
  cnt[t] = 0;
  __syncthreads();
  for (int j = seg0 + t; j < seg1; j += 256)
    atomicAdd(&cnt[(int)(binned[j] >> 32) & 255], 1);
  __syncthreads();
  int c = cnt[t];
  int lane = t & 63, wid = t >> 6;
  int v = c;
#pragma unroll
  for (int d = 1; d < 64; d <<= 1) {
    int u = __shfl_up(v, d, 64);
    if (lane >= d) v += u;
  }
  if (lane == 63) ws[wid] = v;
  __syncthreads();
  if (t == 0) {
    int run = 0;
    for (int k = 0; k < 4; ++k) { wo[k] = run; run += ws[k]; }
  }
  __syncthreads();
  int excl = v - c + wo[wid];
  if (r0 + t < NNODE) {
    row_ptr[r0 + t] = seg0 + excl;
    counts[r0 + t] = c;
  }
  cur[t] = excl;
  __syncthreads();
  for (int j = seg0 + t; j < seg1; j += 256) {
    unsigned long long e = binned[j];
    int off = atomicAdd(&cur[(int)(e >> 32) & 255], 1);
    csr_dst[seg0 + off] = (int)(unsigned)e;
  }
}

// ---------------- prescale: y_init[n] = bf16(table[n] * rsqrt(max(deg,1))) ------------
__global__ __launch_bounds__(256) void prescale_kernel(const float* __restrict__ ut,
                                                       const float* __restrict__ it,
                                                       const int* __restrict__ counts,
                                                       unsigned short* __restrict__ y) {
  int idx = blockIdx.x * 256 + threadIdx.x;   // one 4-dim group per thread
  if (idx >= NNODE * 16) return;
  int n = idx >> 4;
  float sc = rsqrtf(fmaxf((float)counts[n], 1.f));
  const float* srcp = (n < UCNT) ? (ut + (size_t)n * DDIM)
                                 : (it + (size_t)(n - UCNT) * DDIM);
  float4 v = *(const float4*)(srcp + (idx & 15) * 4);
  ushortx4 o;
  o[0] = f2bf(v.x * sc); o[1] = f2bf(v.y * sc);
  o[2] = f2bf(v.z * sc); o[3] = f2bf(v.w * sc);
  *(ushortx4*)(y + (size_t)idx * 4) = o;
}

// ---------------- SpMM over bf16 rows, 8 edges in flight, fp32 accumulate ------------
__global__ __launch_bounds__(256) void spmm_kernel(const unsigned short* __restrict__ y_in,
                                                   const int* __restrict__ row_ptr,
                                                   const int* __restrict__ csr_dst,
                                                   const int* __restrict__ counts,
                                                   const float* __restrict__ noise,
                                                   unsigned short* __restrict__ y_out) {
  int wave = blockIdx.x * 4 + (threadIdx.x >> 6);
  int lane = threadIdx.x & 63;
  if (wave >= NNODE) return;
  int r = wave;
  int beg = row_ptr[r], endp = row_ptr[r + 1];
  int g = lane >> 3, l8 = lane & 7;   // 8 edge-subgroups x 8 dim-slices (8 dims each)
  float acc[8] = {};
  for (int e0 = beg; e0 < endp; e0 += 64) {
    int e = e0 + lane;
    int d = (e < endp) ? __builtin_nontemporal_load(csr_dst + e) : 0;
    int cnt = min(64, endp - e0);
    for (int j = 0; j < cnt; j += 8) {
      int dj = __shfl(d, j + g, 64);
      if (j + g < cnt) {
        ushortx8 hv = *(const ushortx8*)(y_in + (size_t)dj * DDIM + l8 * 8);
#pragma unroll
        for (int k = 0; k < 8; ++k) acc[k] += bf2f(hv[k]);
      }
    }
  }
  // reduce the 8 edge-subgroups (same l8, g varying: xor strides 8,16,32)
#pragma unroll
  for (int m = 8; m <= 32; m <<= 1)
#pragma unroll
    for (int k = 0; k < 8; ++k) acc[k] += __shfl_xor(acc[k], m, 64);
  float sc = rsqrtf(fmaxf((float)counts[r], 1.f));
  floatx4 n0 = __builtin_nontemporal_load((const floatx4*)(noise + (size_t)r * DDIM + l8 * 8));
  floatx4 n1 = __builtin_nontemporal_load((const floatx4*)(noise + (size_t)r * DDIM + l8 * 8 + 4));
  float nf[8] = {n0[0], n0[1], n0[2], n0[3], n1[0], n1[1], n1[2], n1[3]};
  float ss = 0.f;
#pragma unroll
  for (int k = 0; k < 8; ++k) ss += nf[k] * nf[k];
#pragma unroll
  for (int m = 1; m <= 4; m <<= 1) ss += __shfl_xor(ss, m, 64);   // within 8-lane slice group
  float inv = EPS_C / fmaxf(sqrtf(ss), 1e-12f);
  if (g == 0) {
    ushortx8 ov;
#pragma unroll
    for (int k = 0; k < 8; ++k) {
      float x = acc[k] * sc;
      float sgn = (x > 0.f) ? 1.f : ((x < 0.f) ? -1.f : 0.f);
      ov[k] = f2bf((x + sgn * nf[k] * inv) * sc);   // store y = x_out * sc
    }
    *(ushortx8*)(y_out + (size_t)r * DDIM + l8 * 8) = ov;
  }
}

// ---------------- batch gather: BPR, reg, normalized InfoNCE inputs ----------------
__global__ __launch_bounds__(256) void batch_kernel(
    const unsigned short* __restrict__ yb0, const unsigned short* __restrict__ yb1,
    const unsigned short* __restrict__ yb2,
    const float* __restrict__ ut, const float* __restrict__ it,
    const int* __restrict__ counts,
    const int* __restrict__ user, const int* __restrict__ pos, const int* __restrict__ neg,
    float* __restrict__ z1u, float* __restrict__ z2u,
    float* __restrict__ z1i, float* __restrict__ z2i,
    float* __restrict__ pos_u, float* __restrict__ pos_i,
    float* __restrict__ sp_arr, float* __restrict__ rr_arr) {
  int wave = blockIdx.x * (blockDim.x >> 6) + (threadIdx.x >> 6);
  int lane = threadIdx.x & 63;
  if (wave >= BB) return;
  int b = wave;
  int iu = user[b], ip = pos[b], ing = neg[b];
  float s_u = sqrtf(fmaxf((float)counts[iu], 1.f));
  float s_p = sqrtf(fmaxf((float)counts[UCNT + ip], 1.f));
  float s_n = sqrtf(fmaxf((float)counts[UCNT + ing], 1.f));
  size_t ru = (size_t)iu * DDIM + lane;
  size_t rp = (size_t)(UCNT + ip) * DDIM + lane;
  size_t rn = (size_t)(UCNT + ing) * DDIM + lane;
  float cu = bf2f(yb0[ru]) * s_u;        // x_cl user row
  float ci = bf2f(yb0[rp]) * s_p;        // x_cl positive-item row
  float ue = (cu + (bf2f(yb1[ru]) + bf2f(yb2[ru])) * s_u) * (1.f / 3.f);
  float pe = (ci + (bf2f(yb1[rp]) + bf2f(yb2[rp])) * s_p) * (1.f / 3.f);
  float ne = (bf2f(yb0[rn]) + bf2f(yb1[rn]) + bf2f(yb2[rn])) * s_n * (1.f / 3.f);

  float ps = wave_sum(ue * pe);
  float ns = wave_sum(ue * ne);
  float x = ns - ps;
  float sp = fmaxf(x, 0.f) + log1pf(expf(-fabsf(x)));

  float eu = ut[(size_t)iu * DDIM + lane];
  float ep = it[(size_t)ip * DDIM + lane];
  float en = it[(size_t)ing * DDIM + lane];
  float rr = wave_sum(eu * eu + ep * ep + en * en);
  if (lane == 0) { sp_arr[b] = sp; rr_arr[b] = rr; }

  float n1 = fmaxf(sqrtf(wave_sum(cu * cu)), 1e-12f);
  float n2 = fmaxf(sqrtf(wave_sum(ue * ue)), 1e-12f);
  float d12 = wave_sum(cu * ue);
  z1u[(size_t)b * DDIM + lane] = cu / n1;
  z2u[(size_t)b * DDIM + lane] = ue / n2;
  if (lane == 0) pos_u[b] = d12 / (n1 * n2) * INV_TEMP;

  float m1 = fmaxf(sqrtf(wave_sum(ci * ci)), 1e-12f);
  float m2 = fmaxf(sqrtf(wave_sum(pe * pe)), 1e-12f);
  float e12 = wave_sum(ci * pe);
  z1i[(size_t)b * DDIM + lane] = ci / m1;
  z2i[(size_t)b * DDIM + lane] = pe / m2;
  if (lane == 0) pos_i[b] = e12 / (m1 * m2) * INV_TEMP;
}

// ---------------- InfoNCE similarity tile: partial per (jtile,row), NO atomics --------
__global__ __launch_bounds__(256) void infonce_kernel(const float* __restrict__ Z1,
                                                      const float* __restrict__ Z2,
                                                      float* __restrict__ rowpart) {
  __shared__ float S1[64][65];
  __shared__ float S2[64][65];
  __shared__ float red[64][17];
  int t = threadIdx.x;
  int i0 = blockIdx.y * 64, j0 = blockIdx.x * 64;
#pragma unroll
  for (int rep = 0; rep < 4; ++rep) {
    int vlin = rep * 256 + t;       // float4 index in 64x16
    int row = vlin >> 4;
    int c4 = (vlin & 15) * 4;
    float4 a = *(const float4*)(Z1 + (size_t)(i0 + row) * DDIM + c4);
    S1[c4 + 0][row] = a.x; S1[c4 + 1][row] = a.y; S1[c4 + 2][row] = a.z; S1[c4 + 3][row] = a.w;
    float4 b = *(const float4*)(Z2 + (size_t)(j0 + row) * DDIM + c4);
    S2[c4 + 0][row] = b.x; S2[c4 + 1][row] = b.y; S2[c4 + 2][row] = b.z; S2[c4 + 3][row] = b.w;
  }
  __syncthreads();
  int ti = (t & 15) * 4;
  int tj = (t >> 4) * 4;
  float acc[4][4] = {};
  for (int k = 0; k < 64; ++k) {
    float4 av = *(const float4*)&S1[k][ti];
    float4 bv = *(const float4*)&S2[k][tj];
    float a[4] = {av.x, av.y, av.z, av.w};
    float b[4] = {bv.x, bv.y, bv.z, bv.w};
#pragma unroll
    for (int r = 0; r < 4; ++r)
#pragma unroll
      for (int c = 0; c < 4; ++c) acc[r][c] += a[r] * b[c];
  }
  int q = t >> 4;
#pragma unroll
  for (int r = 0; r < 4; ++r) {
    float s = __expf(acc[r][0] * INV_TEMP) + __expf(acc[r][1] * INV_TEMP) +
              __expf(acc[r][2] * INV_TEMP) + __expf(acc[r][3] * INV_TEMP);
    red[ti + r][q] = s;
  }
  __syncthreads();
  if (t < 64) {
    float tot = 0.f;
#pragma unroll
    for (int q2 = 0; q2 < 16; ++q2) tot += red[t][q2];
    rowpart[(size_t)blockIdx.x * BB + i0 + t] = tot;   // coalesced, no atomic
  }
}

// ---------------- reduce 64 partials per row into rowsum ----------------
__global__ __launch_bounds__(256) void reduce_kernel(const float* __restrict__ rowpart_u,
                                                     const float* __restrict__ rowpart_i,
                                                     float* __restrict__ rowsum_u,
                                                     float* __restrict__ rowsum_i) {
  int i = blockIdx.x * 256 + threadIdx.x;   // row index
  const float* src = blockIdx.y ? rowpart_i : rowpart_u;
  float s = 0.f;
#pragma unroll 8
  for (int jb = 0; jb < NJT; ++jb) s += __builtin_nontemporal_load(src + (size_t)jb * BB + i);
  if (blockIdx.y) rowsum_i[i] = s; else rowsum_u[i] = s;
}

// ---------------- finalize ----------------
__global__ __launch_bounds__(256) void finalize_kernel(const float* __restrict__ rowsum_u,
                                                       const float* __restrict__ pos_u,
                                                       const float* __restrict__ rowsum_i,
                                                       const float* __restrict__ pos_i,
                                                       const float* __restrict__ sp_arr,
                                                       const float* __restrict__ rr_arr,
                                                       float* __restrict__ out) {
  int t = threadIdx.x;
  float su = 0.f, si = 0.f, sb = 0.f, sr = 0.f;
  for (int i = t; i < BB; i += 256) {
    su += logf(rowsum_u[i]) - pos_u[i];
    si += logf(rowsum_i[i]) - pos_i[i];
    sb += sp_arr[i];
    sr += rr_arr[i];
  }
  su = wave_sum(su);
  si = wave_sum(si);
  sb = wave_sum(sb);
  sr = wave_sum(sr);
  __shared__ float sh[16];
  int lane = t & 63, wid = t >> 6;
  if (lane == 0) { sh[wid] = su; sh[4 + wid] = si; sh[8 + wid] = sb; sh[12 + wid] = sr; }
  __syncthreads();
  if (t == 0) {
    float SU = sh[0] + sh[1] + sh[2] + sh[3];
    float SI = sh[4] + sh[5] + sh[6] + sh[7];
    float SB = sh[8] + sh[9] + sh[10] + sh[11];
    float SR = sh[12] + sh[13] + sh[14] + sh[15];
    out[0] = SB * (1.f / BB);
    out[1] = 1e-4f * 0.5f * SR * (1.f / BB);
    out[2] = 0.2f * ((SU + SI) * (1.f / BB));
  }
}

extern "C" void kernel_launch(void* const* d_in, const int* in_sizes, int n_in,
                              void* d_out, int out_size, void* d_ws, size_t ws_size,
                              hipStream_t stream) {
  const float* user_table = (const float*)d_in[0];
  const float* item_table = (const float*)d_in[1];
  const float* noise      = (const float*)d_in[3];
  const int*   edge_src   = (const int*)d_in[4];
  const int*   edge_dst   = (const int*)d_in[5];
  const int*   user       = (const int*)d_in[6];
  const int*   positive   = (const int*)d_in[7];
  const int*   negative   = (const int*)d_in[8];
  const int E2 = in_sizes[2];  // 2,000,000

  const int eh = E2 >> 1;
  const int nbu = (eh + EPB - 1) / EPB;            // 245
  const int nbi = (E2 - eh + EPB - 1) / EPB;       // 245
  const int nbp = nbu + nbi;                       // 490

  char* w = (char*)d_ws;
  auto alloc = [&](size_t bytes) -> void* {
    void* p = (void*)w;
    w += (bytes + 255) & ~(size_t)255;
    return p;
  };
  int*   ccnt     = (int*)alloc((size_t)NRANGE * 4);
  int*   cbase    = (int*)alloc((size_t)NRANGE * 4);
  int*   bcnt     = (int*)alloc((size_t)NRANGE * nbp * 4);
  int*   boff     = (int*)alloc((size_t)NRANGE * nbp * 4);
  int*   row_ptr  = (int*)alloc((size_t)(NNODE + 1) * 4);
  int*   counts   = (int*)alloc((size_t)NNODE * 4);
  int*   csr_dst  = (int*)alloc((size_t)E2 * 4);
  unsigned long long* binned = (unsigned long long*)alloc((size_t)E2 * 8);
  unsigned short* y_init = (unsigned short*)alloc((size_t)NNODE * DDIM * 2);
  unsigned short* yb0    = (unsigned short*)alloc((size_t)NNODE * DDIM * 2);
  unsigned short* yb1    = (unsigned short*)alloc((size_t)NNODE * DDIM * 2);
  unsigned short* yb2    = (unsigned short*)alloc((size_t)NNODE * DDIM * 2);
  float* z1u      = (float*)alloc((size_t)BB * DDIM * 4);
  float* z2u      = (float*)alloc((size_t)BB * DDIM * 4);
  float* z1i      = (float*)alloc((size_t)BB * DDIM * 4);
  float* z2i      = (float*)alloc((size_t)BB * DDIM * 4);
  float* pos_u    = (float*)alloc((size_t)BB * 4);
  float* pos_i    = (float*)alloc((size_t)BB * 4);
  float* rowsum_u = (float*)alloc((size_t)BB * 4);
  float* rowsum_i = (float*)alloc((size_t)BB * 4);
  float* sp_arr   = (float*)alloc((size_t)BB * 4);
  float* rr_arr   = (float*)alloc((size_t)BB * 4);
  float* rowpart_u = (float*)alloc((size_t)NJT * BB * 4);
  float* rowpart_i = (float*)alloc((size_t)NJT * BB * 4);

  hipMemsetAsync(ccnt, 0, (size_t)NRANGE * 4, stream);
  hipMemsetAsync(bcnt, 0, (size_t)NRANGE * nbp * 4, stream);
  hist_coarse_kernel<<<512, 256, 0, stream>>>(edge_src, ccnt, E2);
  cscan_kernel<<<1, 512, 0, stream>>>(ccnt, cbase, row_ptr, E2);
  pcount_kernel<<<nbp, 256, 0, stream>>>(edge_src, bcnt, E2, nbu, nbp);
  pscan_kernel<<<NRANGE, 256, 0, stream>>>(bcnt, cbase, boff, nbp);
  pscatter_kernel<<<nbp, 256, 0, stream>>>(edge_src, edge_dst, boff, binned, E2, nbu, nbp);
  place_kernel<<<NRANGE, 256, 0, stream>>>(binned, cbase, row_ptr, counts, csr_dst, E2);
  prescale_kernel<<<(NNODE * 16 + 255) / 256, 256, 0, stream>>>(user_table, item_table,
                                                                counts, y_init);
  const int spmm_blocks = (NNODE + 3) / 4;  // 4 waves per 256-thread block
  spmm_kernel<<<spmm_blocks, 256, 0, stream>>>(y_init, row_ptr, csr_dst, counts,
                                               noise + (size_t)0 * NNODE * DDIM, yb0);
  spmm_kernel<<<spmm_blocks, 256, 0, stream>>>(yb0, row_ptr, csr_dst, counts,
                                               noise + (size_t)1 * NNODE * DDIM, yb1);
  spmm_kernel<<<spmm_blocks, 256, 0, stream>>>(yb1, row_ptr, csr_dst, counts,
                                               noise + (size_t)2 * NNODE * DDIM, yb2);
  batch_kernel<<<BB / 4, 256, 0, stream>>>(yb0, yb1, yb2, user_table, item_table, counts,
                                           user, positive, negative,
                                           z1u, z2u, z1i, z2i, pos_u, pos_i, sp_arr, rr_arr);
  dim3 ig(NJT, NJT);
  infonce_kernel<<<ig, 256, 0, stream>>>(z1u, z2u, rowpart_u);
  infonce_kernel<<<ig, 256, 0, stream>>>(z1i, z2i, rowpart_i);
  dim3 rg(BB / 256, 2);
  reduce_kernel<<<rg, 256, 0, stream>>>(rowpart_u, rowpart_i, rowsum_u, rowsum_i);
  finalize_kernel<<<1, 256, 0, stream>>>(rowsum_u, pos_u, rowsum_i, pos_i,
                                         sp_arr, rr_arr, (float*)d_out);
}

// Round 13
// 443.607 us; speedup vs baseline: 2.4377x; 1.0605x over previous
//
#include <hip/hip_runtime.h>
#include <hip/hip_bf16.h>
#include <math.h>

#define UCNT 50000
#define ICNT 25000
#define NNODE 75000
#define DDIM 64
#define BB 4096
#define EPS_C 0.2f
#define INV_TEMP 5.0f
#define NJT (BB / 64)       // 64 j-tiles in infonce

#define NRANGE 293          // 256-node ranges
#define RB_U 196            // user-half ranges (0..195; range 195 shared w/ items)
#define RB_I 98             // item-half ranges (195..292 -> rel 0..97)
#define GOFF_I 195
#define EPB 4096            // edges per partition block (both halves)

typedef float floatx4 __attribute__((ext_vector_type(4)));
typedef unsigned short ushortx8 __attribute__((ext_vector_type(8)));
typedef unsigned short ushortx4 __attribute__((ext_vector_type(4)));
typedef short shortx8 __attribute__((ext_vector_type(8)));

__device__ __forceinline__ float wave_sum(float x) {
#pragma unroll
  for (int m = 32; m >= 1; m >>= 1) x += __shfl_xor(x, m, 64);
  return x;
}

__device__ __forceinline__ unsigned short f2bf(float f) {   // RNE
  unsigned u = __float_as_uint(f);
  u += 0x7fffu + ((u >> 16) & 1u);
  return (unsigned short)(u >> 16);
}
__device__ __forceinline__ float bf2f(unsigned short h) {
  return __uint_as_float((unsigned)h << 16);
}

// ---------------- coarse histogram over 293 node-ranges ----------------
__global__ __launch_bounds__(256) void hist_coarse_kernel(const int* __restrict__ src,
                                                          int* __restrict__ ccnt, int ne) {
  __shared__ int h[NRANGE];
  int t = threadIdx.x;
  for (int i = t; i < NRANGE; i += 256) h[i] = 0;
  __syncthreads();
  int stride = gridDim.x * 256;
  for (int i = blockIdx.x * 256 + t; i < ne; i += stride) {
    int s = __builtin_nontemporal_load(src + i);
    atomicAdd(&h[s >> 8], 1);
  }
  __syncthreads();
  for (int i = t; i < NRANGE; i += 256)
    if (h[i]) atomicAdd(&ccnt[i], h[i]);
}

// ---------------- scan 293 range counts -> segment bases ----------------
__global__ __launch_bounds__(512) void cscan_kernel(const int* __restrict__ ccnt,
                                                    int* __restrict__ cbase,
                                                    int* __restrict__ row_ptr, int ne) {
  int t = threadIdx.x;
  int lane = t & 63, wid = t >> 6;
  int c = (t < NRANGE) ? ccnt[t] : 0;
  int v = c;
#pragma unroll
  for (int d = 1; d < 64; d <<= 1) {
    int u = __shfl_up(v, d, 64);
    if (lane >= d) v += u;
  }
  __shared__ int ws[8], wo[8];
  if (lane == 63) ws[wid] = v;
  __syncthreads();
  if (t == 0) {
    int run = 0;
    for (int k = 0; k < 8; ++k) { wo[k] = run; run += ws[k]; }
    row_ptr[NNODE] = ne;
  }
  __syncthreads();
  if (t < NRANGE) cbase[t] = v - c + wo[wid];
}

// ---------------- pcount: per (stripe-block, range) histogram -> bcnt ----------------
__global__ __launch_bounds__(256) void pcount_kernel(const int* __restrict__ src,
                                                     int* __restrict__ bcnt,
                                                     int ne, int nbu, int nbp) {
  __shared__ int qc[RB_U];
  int t = threadIdx.x;
  int b = blockIdx.x;
  int eh = ne >> 1;
  bool isU = b < nbu;
  int base = isU ? b * EPB : eh + (b - nbu) * EPB;
  int lim = min(base + EPB, isU ? eh : ne);
  int RB = isU ? RB_U : RB_I;
  int goff = isU ? 0 : GOFF_I;
  for (int i = t; i < RB; i += 256) qc[i] = 0;
  __syncthreads();
  for (int i = base + t; i < lim; i += 256) {
    int s = __builtin_nontemporal_load(src + i);
    atomicAdd(&qc[(s >> 8) - goff], 1);
  }
  __syncthreads();
  for (int r = t; r < RB; r += 256) bcnt[(size_t)(r + goff) * nbp + b] = qc[r];
}

// ---------------- pscan: per range, exclusive scan over block columns ----------------
__global__ __launch_bounds__(256) void pscan_kernel(const int* __restrict__ bcnt,
                                                    const int* __restrict__ cbase,
                                                    int* __restrict__ boff, int nbp) {
  __shared__ int s0[512], s1[512];
  int r = blockIdx.x, t = threadIdx.x;
  for (int j = t; j < 512; j += 256) s0[j] = (j < nbp) ? bcnt[(size_t)r * nbp + j] : 0;
  __syncthreads();
  int* a = s0;
  int* bf = s1;
  for (int off = 1; off < 512; off <<= 1) {
    for (int j = t; j < 512; j += 256) bf[j] = a[j] + ((j >= off) ? a[j - off] : 0);
    __syncthreads();
    int* tmp = a; a = bf; bf = tmp;
  }
  int base = cbase[r];
  for (int j = t; j < nbp; j += 256)
    boff[(size_t)r * nbp + j] = base + a[j] - bcnt[(size_t)r * nbp + j];
}

// ---------------- pscatter: deterministic binning (no global atomics) ----------------
__global__ __launch_bounds__(256) void pscatter_kernel(const int* __restrict__ src,
                                                       const int* __restrict__ dst,
                                                       const int* __restrict__ boff,
                                                       unsigned long long* __restrict__ binned,
                                                       int ne, int nbu, int nbp) {
  __shared__ int qc[RB_U];
  int t = threadIdx.x;
  int b = blockIdx.x;
  int eh = ne >> 1;
  bool isU = b < nbu;
  int base = isU ? b * EPB : eh + (b - nbu) * EPB;
  int lim = min(base + EPB, isU ? eh : ne);
  int goff = isU ? 0 : GOFF_I;
  int RB = isU ? RB_U : RB_I;
  for (int i = t; i < RB; i += 256) qc[i] = 0;
  __syncthreads();
  for (int i = base + t; i < lim; i += 256) {
    int s = __builtin_nontemporal_load(src + i);
    int d = __builtin_nontemporal_load(dst + i);
    int rb = (s >> 8) - goff;
    int pos = atomicAdd(&qc[rb], 1);
    int g = boff[(size_t)(rb + goff) * nbp + b] + pos;
    binned[g] = ((unsigned long long)(unsigned)s << 32) | (unsigned)d;
  }
}

// ---------------- place: one block per range -> row_ptr, counts, csr (private region)
__global__ __launch_bounds__(256) void place_kernel(
    const unsigned long long* __restrict__ binned, const int* __restrict__ cbase,
    int* __restrict__ row_ptr, int* __restrict__ counts,
    int* __restrict__ csr_dst, int ne) {
  __shared__ int cnt[256], cur[256], ws[4], wo[4];
  int t = threadIdx.x;
  int b = blockIdx.x;
  int r0 = b << 8;
  int seg0 = cbase[b];
  int seg1 = (b == NRANGE - 1) ? ne : cbase[b + 1];
  cnt[t] = 0;
  __syncthreads();
  for (int j = seg0 + t; j < seg1; j += 256)
    atomicAdd(&cnt[(int)(binned[j] >> 32) & 255], 1);
  __syncthreads();
  int c = cnt[t];
  int lane = t & 63, wid = t >> 6;
  int v = c;
#pragma unroll
  for (int d = 1; d < 64; d <<= 1) {
    int u = __shfl_up(v, d, 64);
    if (lane >= d) v += u;
  }
  if (lane == 63) ws[wid] = v;
  __syncthreads();
  if (t == 0) {
    int run = 0;
    for (int k = 0; k < 4; ++k) { wo[k] = run; run += ws[k]; }
  }
  __syncthreads();
  int excl = v - c + wo[wid];
  if (r0 + t < NNODE) {
    row_ptr[r0 + t] = seg0 + excl;
    counts[r0 + t] = c;
  }
  cur[t] = excl;
  __syncthreads();
  for (int j = seg0 + t; j < seg1; j += 256) {
    unsigned long long e = binned[j];
    int off = atomicAdd(&cur[(int)(e >> 32) & 255], 1);
    csr_dst[seg0 + off] = (int)(unsigned)e;
  }
}

// ---------------- prescale: y_init[n] = bf16(table[n] * rsqrt(max(deg,1))) ------------
__global__ __launch_bounds__(256) void prescale_kernel(const float* __restrict__ ut,
                                                       const float* __restrict__ it,
                                                       const int* __restrict__ counts,
                                                       unsigned short* __restrict__ y) {
  int idx = blockIdx.x * 256 + threadIdx.x;   // one 4-dim group per thread
  if (idx >= NNODE * 16) return;
  int n = idx >> 4;
  float sc = rsqrtf(fmaxf((float)counts[n], 1.f));
  const float* srcp = (n < UCNT) ? (ut + (size_t)n * DDIM)
                                 : (it + (size_t)(n - UCNT) * DDIM);
  float4 v = *(const float4*)(srcp + (idx & 15) * 4);
  ushortx4 o;
  o[0] = f2bf(v.x * sc); o[1] = f2bf(v.y * sc);
  o[2] = f2bf(v.z * sc); o[3] = f2bf(v.w * sc);
  *(ushortx4*)(y + (size_t)idx * 4) = o;
}

// ---------------- SpMM over bf16 rows, 8 edges in flight, fp32 accumulate ------------
__global__ __launch_bounds__(256) void spmm_kernel(const unsigned short* __restrict__ y_in,
                                                   const int* __restrict__ row_ptr,
                                                   const int* __restrict__ csr_dst,
                                                   const int* __restrict__ counts,
                                                   const float* __restrict__ noise,
                                                   unsigned short* __restrict__ y_out) {
  int wave = blockIdx.x * 4 + (threadIdx.x >> 6);
  int lane = threadIdx.x & 63;
  if (wave >= NNODE) return;
  int r = wave;
  int beg = row_ptr[r], endp = row_ptr[r + 1];
  int g = lane >> 3, l8 = lane & 7;   // 8 edge-subgroups x 8 dim-slices (8 dims each)
  float acc[8] = {};
  for (int e0 = beg; e0 < endp; e0 += 64) {
    int e = e0 + lane;
    int d = (e < endp) ? __builtin_nontemporal_load(csr_dst + e) : 0;
    int cnt = min(64, endp - e0);
    for (int j = 0; j < cnt; j += 8) {
      int dj = __shfl(d, j + g, 64);
      if (j + g < cnt) {
        ushortx8 hv = *(const ushortx8*)(y_in + (size_t)dj * DDIM + l8 * 8);
#pragma unroll
        for (int k = 0; k < 8; ++k) acc[k] += bf2f(hv[k]);
      }
    }
  }
#pragma unroll
  for (int m = 8; m <= 32; m <<= 1)
#pragma unroll
    for (int k = 0; k < 8; ++k) acc[k] += __shfl_xor(acc[k], m, 64);
  float sc = rsqrtf(fmaxf((float)counts[r], 1.f));
  floatx4 n0 = __builtin_nontemporal_load((const floatx4*)(noise + (size_t)r * DDIM + l8 * 8));
  floatx4 n1 = __builtin_nontemporal_load((const floatx4*)(noise + (size_t)r * DDIM + l8 * 8 + 4));
  float nf[8] = {n0[0], n0[1], n0[2], n0[3], n1[0], n1[1], n1[2], n1[3]};
  float ss = 0.f;
#pragma unroll
  for (int k = 0; k < 8; ++k) ss += nf[k] * nf[k];
#pragma unroll
  for (int m = 1; m <= 4; m <<= 1) ss += __shfl_xor(ss, m, 64);   // within 8-lane slice group
  float inv = EPS_C / fmaxf(sqrtf(ss), 1e-12f);
  if (g == 0) {
    ushortx8 ov;
#pragma unroll
    for (int k = 0; k < 8; ++k) {
      float x = acc[k] * sc;
      float sgn = (x > 0.f) ? 1.f : ((x < 0.f) ? -1.f : 0.f);
      ov[k] = f2bf((x + sgn * nf[k] * inv) * sc);   // store y = x_out * sc
    }
    *(ushortx8*)(y_out + (size_t)r * DDIM + l8 * 8) = ov;
  }
}

// ---------------- batch gather: BPR, reg, bf16 normalized InfoNCE inputs -------------
__global__ __launch_bounds__(256) void batch_kernel(
    const unsigned short* __restrict__ yb0, const unsigned short* __restrict__ yb1,
    const unsigned short* __restrict__ yb2,
    const float* __restrict__ ut, const float* __restrict__ it,
    const int* __restrict__ counts,
    const int* __restrict__ user, const int* __restrict__ pos, const int* __restrict__ neg,
    unsigned short* __restrict__ z1u, unsigned short* __restrict__ z2u,
    unsigned short* __restrict__ z1i, unsigned short* __restrict__ z2i,
    float* __restrict__ pos_u, float* __restrict__ pos_i,
    float* __restrict__ sp_arr, float* __restrict__ rr_arr) {
  int wave = blockIdx.x * (blockDim.x >> 6) + (threadIdx.x >> 6);
  int lane = threadIdx.x & 63;
  if (wave >= BB) return;
  int b = wave;
  int iu = user[b], ip = pos[b], ing = neg[b];
  float s_u = sqrtf(fmaxf((float)counts[iu], 1.f));
  float s_p = sqrtf(fmaxf((float)counts[UCNT + ip], 1.f));
  float s_n = sqrtf(fmaxf((float)counts[UCNT + ing], 1.f));
  size_t ru = (size_t)iu * DDIM + lane;
  size_t rp = (size_t)(UCNT + ip) * DDIM + lane;
  size_t rn = (size_t)(UCNT + ing) * DDIM + lane;
  float cu = bf2f(yb0[ru]) * s_u;        // x_cl user row
  float ci = bf2f(yb0[rp]) * s_p;        // x_cl positive-item row
  float ue = (cu + (bf2f(yb1[ru]) + bf2f(yb2[ru])) * s_u) * (1.f / 3.f);
  float pe = (ci + (bf2f(yb1[rp]) + bf2f(yb2[rp])) * s_p) * (1.f / 3.f);
  float ne = (bf2f(yb0[rn]) + bf2f(yb1[rn]) + bf2f(yb2[rn])) * s_n * (1.f / 3.f);

  float ps = wave_sum(ue * pe);
  float ns = wave_sum(ue * ne);
  float x = ns - ps;
  float sp = fmaxf(x, 0.f) + log1pf(expf(-fabsf(x)));

  float eu = ut[(size_t)iu * DDIM + lane];
  float ep = it[(size_t)ip * DDIM + lane];
  float en = it[(size_t)ing * DDIM + lane];
  float rr = wave_sum(eu * eu + ep * ep + en * en);
  if (lane == 0) { sp_arr[b] = sp; rr_arr[b] = rr; }

  float n1 = fmaxf(sqrtf(wave_sum(cu * cu)), 1e-12f);
  float n2 = fmaxf(sqrtf(wave_sum(ue * ue)), 1e-12f);
  float d12 = wave_sum(cu * ue);
  z1u[(size_t)b * DDIM + lane] = f2bf(cu / n1);
  z2u[(size_t)b * DDIM + lane] = f2bf(ue / n2);
  if (lane == 0) pos_u[b] = d12 / (n1 * n2) * INV_TEMP;

  float m1 = fmaxf(sqrtf(wave_sum(ci * ci)), 1e-12f);
  float m2 = fmaxf(sqrtf(wave_sum(pe * pe)), 1e-12f);
  float e12 = wave_sum(ci * pe);
  z1i[(size_t)b * DDIM + lane] = f2bf(ci / m1);
  z2i[(size_t)b * DDIM + lane] = f2bf(pe / m2);
  if (lane == 0) pos_i[b] = e12 / (m1 * m2) * INV_TEMP;
}

// ---------------- InfoNCE via MFMA: one wave = 16x16 tile, K=64 ----------------------
// A/B frags: row=lane&15, k=(lane>>4)*8+j (consistent k-permutation cancels in the dot).
// C/D layout (verified m89): col=lane&15, row=(lane>>4)*4+reg.
__global__ __launch_bounds__(256) void infonce_kernel(const unsigned short* __restrict__ Z1,
                                                      const unsigned short* __restrict__ Z2,
                                                      float* __restrict__ rowpart) {
  __shared__ float part[16];
  int t = threadIdx.x;
  if (t < 16) part[t] = 0.f;
  __syncthreads();
  int wv = t >> 6, lane = t & 63;
  int i0 = blockIdx.y * 16;              // 16-row i-tile (shared by 4 waves)
  int j0 = blockIdx.x * 64 + wv * 16;    // each wave: its own 16-col group
  int m = lane & 15, q = lane >> 4;
  const unsigned short* ap = Z1 + (size_t)(i0 + m) * DDIM + q * 8;
  const unsigned short* bp = Z2 + (size_t)(j0 + m) * DDIM + q * 8;
  shortx8 a0 = *(const shortx8*)ap;
  shortx8 a1 = *(const shortx8*)(ap + 32);
  shortx8 b0 = *(const shortx8*)bp;
  shortx8 b1 = *(const shortx8*)(bp + 32);
  floatx4 acc = {0.f, 0.f, 0.f, 0.f};
  acc = __builtin_amdgcn_mfma_f32_16x16x32_bf16(a0, b0, acc, 0, 0, 0);
  acc = __builtin_amdgcn_mfma_f32_16x16x32_bf16(a1, b1, acc, 0, 0, 0);
  float s[4];
#pragma unroll
  for (int r = 0; r < 4; ++r) s[r] = __expf(acc[r] * INV_TEMP);
#pragma unroll
  for (int mm = 1; mm <= 8; mm <<= 1)
#pragma unroll
    for (int r = 0; r < 4; ++r) s[r] += __shfl_xor(s[r], mm, 64);
  if (m == 0) {
#pragma unroll
    for (int r = 0; r < 4; ++r) atomicAdd(&part[q * 4 + r], s[r]);
  }
  __syncthreads();
  if (t < 16) rowpart[(size_t)blockIdx.x * BB + i0 + t] = part[t];
}

// ---------------- reduce 64 partials per row into rowsum ----------------
__global__ __launch_bounds__(256) void reduce_kernel(const float* __restrict__ rowpart_u,
                                                     const float* __restrict__ rowpart_i,
                                                     float* __restrict__ rowsum_u,
                                                     float* __restrict__ rowsum_i) {
  int i = blockIdx.x * 256 + threadIdx.x;   // row index
  const float* src = blockIdx.y ? rowpart_i : rowpart_u;
  float s = 0.f;
#pragma unroll 8
  for (int jb = 0; jb < NJT; ++jb) s += __builtin_nontemporal_load(src + (size_t)jb * BB + i);
  if (blockIdx.y) rowsum_i[i] = s; else rowsum_u[i] = s;
}

// ---------------- finalize ----------------
__global__ __launch_bounds__(256) void finalize_kernel(const float* __restrict__ rowsum_u,
                                                       const float* __restrict__ pos_u,
                                                       const float* __restrict__ rowsum_i,
                                                       const float* __restrict__ pos_i,
                                                       const float* __restrict__ sp_arr,
                                                       const float* __restrict__ rr_arr,
                                                       float* __restrict__ out) {
  int t = threadIdx.x;
  float su = 0.f, si = 0.f, sb = 0.f, sr = 0.f;
  for (int i = t; i < BB; i += 256) {
    su += logf(rowsum_u[i]) - pos_u[i];
    si += logf(rowsum_i[i]) - pos_i[i];
    sb += sp_arr[i];
    sr += rr_arr[i];
  }
  su = wave_sum(su);
  si = wave_sum(si);
  sb = wave_sum(sb);
  sr = wave_sum(sr);
  __shared__ float sh[16];
  int lane = t & 63, wid = t >> 6;
  if (lane == 0) { sh[wid] = su; sh[4 + wid] = si; sh[8 + wid] = sb; sh[12 + wid] = sr; }
  __syncthreads();
  if (t == 0) {
    float SU = sh[0] + sh[1] + sh[2] + sh[3];
    float SI = sh[4] + sh[5] + sh[6] + sh[7];
    float SB = sh[8] + sh[9] + sh[10] + sh[11];
    float SR = sh[12] + sh[13] + sh[14] + sh[15];
    out[0] = SB * (1.f / BB);
    out[1] = 1e-4f * 0.5f * SR * (1.f / BB);
    out[2] = 0.2f * ((SU + SI) * (1.f / BB));
  }
}

extern "C" void kernel_launch(void* const* d_in, const int* in_sizes, int n_in,
                              void* d_out, int out_size, void* d_ws, size_t ws_size,
                              hipStream_t stream) {
  const float* user_table = (const float*)d_in[0];
  const float* item_table = (const float*)d_in[1];
  const float* noise      = (const float*)d_in[3];
  const int*   edge_src   = (const int*)d_in[4];
  const int*   edge_dst   = (const int*)d_in[5];
  const int*   user       = (const int*)d_in[6];
  const int*   positive   = (const int*)d_in[7];
  const int*   negative   = (const int*)d_in[8];
  const int E2 = in_sizes[2];  // 2,000,000

  const int eh = E2 >> 1;
  const int nbu = (eh + EPB - 1) / EPB;            // 245
  const int nbi = (E2 - eh + EPB - 1) / EPB;       // 245
  const int nbp = nbu + nbi;                       // 490

  char* w = (char*)d_ws;
  auto alloc = [&](size_t bytes) -> void* {
    void* p = (void*)w;
    w += (bytes + 255) & ~(size_t)255;
    return p;
  };
  int*   ccnt     = (int*)alloc((size_t)NRANGE * 4);
  int*   cbase    = (int*)alloc((size_t)NRANGE * 4);
  int*   bcnt     = (int*)alloc((size_t)NRANGE * nbp * 4);
  int*   boff     = (int*)alloc((size_t)NRANGE * nbp * 4);
  int*   row_ptr  = (int*)alloc((size_t)(NNODE + 1) * 4);
  int*   counts   = (int*)alloc((size_t)NNODE * 4);
  int*   csr_dst  = (int*)alloc((size_t)E2 * 4);
  unsigned long long* binned = (unsigned long long*)alloc((size_t)E2 * 8);
  unsigned short* y_init = (unsigned short*)alloc((size_t)NNODE * DDIM * 2);
  unsigned short* yb0    = (unsigned short*)alloc((size_t)NNODE * DDIM * 2);
  unsigned short* yb1    = (unsigned short*)alloc((size_t)NNODE * DDIM * 2);
  unsigned short* yb2    = (unsigned short*)alloc((size_t)NNODE * DDIM * 2);
  unsigned short* z1u    = (unsigned short*)alloc((size_t)BB * DDIM * 2);
  unsigned short* z2u    = (unsigned short*)alloc((size_t)BB * DDIM * 2);
  unsigned short* z1i    = (unsigned short*)alloc((size_t)BB * DDIM * 2);
  unsigned short* z2i    = (unsigned short*)alloc((size_t)BB * DDIM * 2);
  float* pos_u    = (float*)alloc((size_t)BB * 4);
  float* pos_i    = (float*)alloc((size_t)BB * 4);
  float* rowsum_u = (float*)alloc((size_t)BB * 4);
  float* rowsum_i = (float*)alloc((size_t)BB * 4);
  float* sp_arr   = (float*)alloc((size_t)BB * 4);
  float* rr_arr   = (float*)alloc((size_t)BB * 4);
  float* rowpart_u = (float*)alloc((size_t)NJT * BB * 4);
  float* rowpart_i = (float*)alloc((size_t)NJT * BB * 4);

  hipMemsetAsync(ccnt, 0, (size_t)NRANGE * 4, stream);
  hipMemsetAsync(bcnt, 0, (size_t)NRANGE * nbp * 4, stream);
  hist_coarse_kernel<<<512, 256, 0, stream>>>(edge_src, ccnt, E2);
  cscan_kernel<<<1, 512, 0, stream>>>(ccnt, cbase, row_ptr, E2);
  pcount_kernel<<<nbp, 256, 0, stream>>>(edge_src, bcnt, E2, nbu, nbp);
  pscan_kernel<<<NRANGE, 256, 0, stream>>>(bcnt, cbase, boff, nbp);
  pscatter_kernel<<<nbp, 256, 0, stream>>>(edge_src, edge_dst, boff, binned, E2, nbu, nbp);
  place_kernel<<<NRANGE, 256, 0, stream>>>(binned, cbase, row_ptr, counts, csr_dst, E2);
  prescale_kernel<<<(NNODE * 16 + 255) / 256, 256, 0, stream>>>(user_table, item_table,
                                                                counts, y_init);
  const int spmm_blocks = (NNODE + 3) / 4;  // 4 waves per 256-thread block
  spmm_kernel<<<spmm_blocks, 256, 0, stream>>>(y_init, row_ptr, csr_dst, counts,
                                               noise + (size_t)0 * NNODE * DDIM, yb0);
  spmm_kernel<<<spmm_blocks, 256, 0, stream>>>(yb0, row_ptr, csr_dst, counts,
                                               noise + (size_t)1 * NNODE * DDIM, yb1);
  spmm_kernel<<<spmm_blocks, 256, 0, stream>>>(yb1, row_ptr, csr_dst, counts,
                                               noise + (size_t)2 * NNODE * DDIM, yb2);
  batch_kernel<<<BB / 4, 256, 0, stream>>>(yb0, yb1, yb2, user_table, item_table, counts,
                                           user, positive, negative,
                                           z1u, z2u, z1i, z2i, pos_u, pos_i, sp_arr, rr_arr);
  dim3 ig(NJT, BB / 16);
  infonce_kernel<<<ig, 256, 0, stream>>>(z1u, z2u, rowpart_u);
  infonce_kernel<<<ig, 256, 0, stream>>>(z1i, z2i, rowpart_i);
  dim3 rg(BB / 256, 2);
  reduce_kernel<<<rg, 256, 0, stream>>>(rowpart_u, rowpart_i, rowsum_u, rowsum_i);
  finalize_kernel<<<1, 256, 0, stream>>>(rowsum_u, pos_u, rowsum_i, pos_i,
                                         sp_arr, rr_arr, (float*)d_out);
}

// Round 14
// 430.343 us; speedup vs baseline: 2.5128x; 1.0308x over previous
//
#include <hip/hip_runtime.h>
#include <hip/hip_bf16.h>
#include <hip/hip_fp8.h>
#include <math.h>

#define UCNT 50000
#define ICNT 25000
#define NNODE 75000
#define DDIM 64
#define BB 4096
#define EPS_C 0.2f
#define INV_TEMP 5.0f
#define NJT (BB / 64)       // 64 j-tiles in infonce

#define NRANGE 293          // 256-node ranges
#define RB_U 196            // user-half ranges (0..195; range 195 shared w/ items)
#define RB_I 98             // item-half ranges (195..292 -> rel 0..97)
#define GOFF_I 195
#define EPB 4096            // edges per partition block (both halves)
#define YS 64.0f            // fp8 y scale (keeps elements in e4m3 normal range)
#define YSI (1.0f / 64.0f)

typedef float floatx4 __attribute__((ext_vector_type(4)));
typedef unsigned short ushortx4 __attribute__((ext_vector_type(4)));
typedef short shortx8 __attribute__((ext_vector_type(8)));

__device__ __forceinline__ float wave_sum(float x) {
#pragma unroll
  for (int m = 32; m >= 1; m >>= 1) x += __shfl_xor(x, m, 64);
  return x;
}

__device__ __forceinline__ unsigned short f2bf(float f) {   // RNE
  unsigned u = __float_as_uint(f);
  u += 0x7fffu + ((u >> 16) & 1u);
  return (unsigned short)(u >> 16);
}
__device__ __forceinline__ float fp8dec(unsigned char b) {
  __hip_fp8_e4m3 h; h.__x = b; return (float)h;
}
__device__ __forceinline__ unsigned char fp8enc(float f) {
  __hip_fp8_e4m3 h(f); return h.__x;
}

// ---------------- pcount: per (stripe-block, range) histogram -> bcnt column ---------
// Each block writes its ENTIRE bcnt column (zeros for the foreign half) -> no memset.
__global__ __launch_bounds__(256) void pcount_kernel(const int* __restrict__ src,
                                                     int* __restrict__ bcnt,
                                                     int ne, int nbu, int nbp) {
  __shared__ int qc[RB_U];
  int t = threadIdx.x;
  int b = blockIdx.x;
  int eh = ne >> 1;
  bool isU = b < nbu;
  int base = isU ? b * EPB : eh + (b - nbu) * EPB;
  int lim = min(base + EPB, isU ? eh : ne);
  int RB = isU ? RB_U : RB_I;
  int goff = isU ? 0 : GOFF_I;
  for (int i = t; i < RB; i += 256) qc[i] = 0;
  __syncthreads();
  for (int i = base + t; i < lim; i += 256) {
    int s = __builtin_nontemporal_load(src + i);
    atomicAdd(&qc[(s >> 8) - goff], 1);
  }
  __syncthreads();
  for (int r = t; r < NRANGE; r += 256) {
    int rel = r - goff;
    int v = (rel >= 0 && rel < RB) ? qc[rel] : 0;
    bcnt[(size_t)r * nbp + b] = v;
  }
}

// ---------------- pscan: per range, local exclusive scan over block columns ----------
// boff gets the LOCAL offsets (no cbase); rtot[r] = range total.
__global__ __launch_bounds__(256) void pscan_kernel(const int* __restrict__ bcnt,
                                                    int* __restrict__ boff,
                                                    int* __restrict__ rtot, int nbp) {
  __shared__ int s0[512], s1[512];
  int r = blockIdx.x, t = threadIdx.x;
  for (int j = t; j < 512; j += 256) s0[j] = (j < nbp) ? bcnt[(size_t)r * nbp + j] : 0;
  __syncthreads();
  int* a = s0;
  int* bf = s1;
  for (int off = 1; off < 512; off <<= 1) {
    for (int j = t; j < 512; j += 256) bf[j] = a[j] + ((j >= off) ? a[j - off] : 0);
    __syncthreads();
    int* tmp = a; a = bf; bf = tmp;
  }
  for (int j = t; j < nbp; j += 256)
    boff[(size_t)r * nbp + j] = a[j] - bcnt[(size_t)r * nbp + j];
  if (t == 0) rtot[r] = a[511];
}

// ---------------- cscan2: scan 293 range totals -> cbase ----------------
__global__ __launch_bounds__(512) void cscan2_kernel(const int* __restrict__ rtot,
                                                     int* __restrict__ cbase,
                                                     int* __restrict__ row_ptr, int ne) {
  int t = threadIdx.x;
  int lane = t & 63, wid = t >> 6;
  int c = (t < NRANGE) ? rtot[t] : 0;
  int v = c;
#pragma unroll
  for (int d = 1; d < 64; d <<= 1) {
    int u = __shfl_up(v, d, 64);
    if (lane >= d) v += u;
  }
  __shared__ int ws[8], wo[8];
  if (lane == 63) ws[wid] = v;
  __syncthreads();
  if (t == 0) {
    int run = 0;
    for (int k = 0; k < 8; ++k) { wo[k] = run; run += ws[k]; }
    row_ptr[NNODE] = ne;
  }
  __syncthreads();
  if (t < NRANGE) cbase[t] = v - c + wo[wid];
}

// ---------------- pscatter: deterministic binning into u32 (srcLow8 | dst) -----------
__global__ __launch_bounds__(256) void pscatter_kernel(const int* __restrict__ src,
                                                       const int* __restrict__ dst,
                                                       const int* __restrict__ boff,
                                                       const int* __restrict__ cbase,
                                                       unsigned* __restrict__ binned,
                                                       int ne, int nbu, int nbp) {
  __shared__ int qc[RB_U];
  int t = threadIdx.x;
  int b = blockIdx.x;
  int eh = ne >> 1;
  bool isU = b < nbu;
  int base = isU ? b * EPB : eh + (b - nbu) * EPB;
  int lim = min(base + EPB, isU ? eh : ne);
  int goff = isU ? 0 : GOFF_I;
  int RB = isU ? RB_U : RB_I;
  for (int i = t; i < RB; i += 256) qc[i] = 0;
  __syncthreads();
  for (int i = base + t; i < lim; i += 256) {
    int s = __builtin_nontemporal_load(src + i);
    int d = __builtin_nontemporal_load(dst + i);
    int rb = (s >> 8) - goff;
    int pos = atomicAdd(&qc[rb], 1);
    int rg = rb + goff;
    int g = cbase[rg] + boff[(size_t)rg * nbp + b] + pos;
    binned[g] = ((unsigned)(s & 255) << 24) | (unsigned)d;   // dst < 2^24
  }
}

// ---------------- place: one block per range -> row_ptr, counts, csr (private region)
__global__ __launch_bounds__(256) void place_kernel(
    const unsigned* __restrict__ binned, const int* __restrict__ cbase,
    int* __restrict__ row_ptr, int* __restrict__ counts,
    int* __restrict__ csr_dst, int ne) {
  __shared__ int cnt[256], cur[256], ws[4], wo[4];
  int t = threadIdx.x;
  int b = blockIdx.x;
  int r0 = b << 8;
  int seg0 = cbase[b];
  int seg1 = (b == NRANGE - 1) ? ne : cbase[b + 1];
  cnt[t] = 0;
  __syncthreads();
  for (int j = seg0 + t; j < seg1; j += 256)
    atomicAdd(&cnt[binned[j] >> 24], 1);
  __syncthreads();
  int c = cnt[t];
  int lane = t & 63, wid = t >> 6;
  int v = c;
#pragma unroll
  for (int d = 1; d < 64; d <<= 1) {
    int u = __shfl_up(v, d, 64);
    if (lane >= d) v += u;
  }
  if (lane == 63) ws[wid] = v;
  __syncthreads();
  if (t == 0) {
    int run = 0;
    for (int k = 0; k < 4; ++k) { wo[k] = run; run += ws[k]; }
  }
  __syncthreads();
  int excl = v - c + wo[wid];
  if (r0 + t < NNODE) {
    row_ptr[r0 + t] = seg0 + excl;
    counts[r0 + t] = c;
  }
  cur[t] = excl;
  __syncthreads();
  for (int j = seg0 + t; j < seg1; j += 256) {
    unsigned e = binned[j];
    int off = atomicAdd(&cur[e >> 24], 1);
    csr_dst[seg0 + off] = (int)(e & 0xFFFFFFu);
  }
}

// ---------------- prescale: y_init[n] = fp8(table[n] * rsqrt(max(deg,1)) * YS) -------
__global__ __launch_bounds__(256) void prescale_kernel(const float* __restrict__ ut,
                                                       const float* __restrict__ it,
                                                       const int* __restrict__ counts,
                                                       unsigned char* __restrict__ y) {
  int idx = blockIdx.x * 256 + threadIdx.x;   // one 4-dim group per thread
  if (idx >= NNODE * 16) return;
  int n = idx >> 4;
  float sc = rsqrtf(fmaxf((float)counts[n], 1.f)) * YS;
  const float* srcp = (n < UCNT) ? (ut + (size_t)n * DDIM)
                                 : (it + (size_t)(n - UCNT) * DDIM);
  float4 v = *(const float4*)(srcp + (idx & 15) * 4);
  uchar4 o;
  o.x = fp8enc(v.x * sc); o.y = fp8enc(v.y * sc);
  o.z = fp8enc(v.z * sc); o.w = fp8enc(v.w * sc);
  *(uchar4*)(y + (size_t)idx * 4) = o;
}

// ---------------- SpMM over fp8 rows, 8 edges in flight, fp32 accumulate -------------
__global__ __launch_bounds__(256) void spmm_kernel(const unsigned char* __restrict__ y_in,
                                                   const int* __restrict__ row_ptr,
                                                   const int* __restrict__ csr_dst,
                                                   const int* __restrict__ counts,
                                                   const float* __restrict__ noise,
                                                   unsigned char* __restrict__ y_out) {
  int wave = blockIdx.x * 4 + (threadIdx.x >> 6);
  int lane = threadIdx.x & 63;
  if (wave >= NNODE) return;
  int r = wave;
  int beg = row_ptr[r], endp = row_ptr[r + 1];
  int g = lane >> 3, l8 = lane & 7;   // 8 edge-subgroups x 8 dim-slices (8 dims each)
  float acc[8] = {};
  for (int e0 = beg; e0 < endp; e0 += 64) {
    int e = e0 + lane;
    int d = (e < endp) ? __builtin_nontemporal_load(csr_dst + e) : 0;
    int cnt = min(64, endp - e0);
    for (int j = 0; j < cnt; j += 8) {
      int dj = __shfl(d, j + g, 64);
      if (j + g < cnt) {
        union { uint2 u; unsigned char c[8]; } pk;
        pk.u = *(const uint2*)(y_in + (size_t)dj * DDIM + l8 * 8);
#pragma unroll
        for (int k = 0; k < 8; ++k) acc[k] += fp8dec(pk.c[k]);
      }
    }
  }
#pragma unroll
  for (int m = 8; m <= 32; m <<= 1)
#pragma unroll
    for (int k = 0; k < 8; ++k) acc[k] += __shfl_xor(acc[k], m, 64);
  float sc = rsqrtf(fmaxf((float)counts[r], 1.f));
  floatx4 n0 = __builtin_nontemporal_load((const floatx4*)(noise + (size_t)r * DDIM + l8 * 8));
  floatx4 n1 = __builtin_nontemporal_load((const floatx4*)(noise + (size_t)r * DDIM + l8 * 8 + 4));
  float nf[8] = {n0[0], n0[1], n0[2], n0[3], n1[0], n1[1], n1[2], n1[3]};
  float ss = 0.f;
#pragma unroll
  for (int k = 0; k < 8; ++k) ss += nf[k] * nf[k];
#pragma unroll
  for (int m = 1; m <= 4; m <<= 1) ss += __shfl_xor(ss, m, 64);   // within 8-lane slice group
  float inv = EPS_C / fmaxf(sqrtf(ss), 1e-12f);
  if (g == 0) {
    unsigned char ov[8];
#pragma unroll
    for (int k = 0; k < 8; ++k) {
      float x = acc[k] * sc * YSI;           // undo fp8 scale from gathered terms
      float sgn = (x > 0.f) ? 1.f : ((x < 0.f) ? -1.f : 0.f);
      ov[k] = fp8enc((x + sgn * nf[k] * inv) * sc * YS);   // store y = x_out * sc (scaled)
    }
    *(uint2*)(y_out + (size_t)r * DDIM + l8 * 8) = *(uint2*)ov;
  }
}

// ---------------- batch gather: BPR, reg, bf16 normalized InfoNCE inputs -------------
__global__ __launch_bounds__(256) void batch_kernel(
    const unsigned char* __restrict__ yb0, const unsigned char* __restrict__ yb1,
    const unsigned char* __restrict__ yb2,
    const float* __restrict__ ut, const float* __restrict__ it,
    const int* __restrict__ counts,
    const int* __restrict__ user, const int* __restrict__ pos, const int* __restrict__ neg,
    unsigned short* __restrict__ z1u, unsigned short* __restrict__ z2u,
    unsigned short* __restrict__ z1i, unsigned short* __restrict__ z2i,
    float* __restrict__ pos_u, float* __restrict__ pos_i,
    float* __restrict__ sp_arr, float* __restrict__ rr_arr) {
  int wave = blockIdx.x * (blockDim.x >> 6) + (threadIdx.x >> 6);
  int lane = threadIdx.x & 63;
  if (wave >= BB) return;
  int b = wave;
  int iu = user[b], ip = pos[b], ing = neg[b];
  float s_u = sqrtf(fmaxf((float)counts[iu], 1.f)) * YSI;
  float s_p = sqrtf(fmaxf((float)counts[UCNT + ip], 1.f)) * YSI;
  float s_n = sqrtf(fmaxf((float)counts[UCNT + ing], 1.f)) * YSI;
  size_t ru = (size_t)iu * DDIM + lane;
  size_t rp = (size_t)(UCNT + ip) * DDIM + lane;
  size_t rn = (size_t)(UCNT + ing) * DDIM + lane;
  float cu = fp8dec(yb0[ru]) * s_u;        // x_cl user row
  float ci = fp8dec(yb0[rp]) * s_p;        // x_cl positive-item row
  float ue = (cu + (fp8dec(yb1[ru]) + fp8dec(yb2[ru])) * s_u) * (1.f / 3.f);
  float pe = (ci + (fp8dec(yb1[rp]) + fp8dec(yb2[rp])) * s_p) * (1.f / 3.f);
  float ne = (fp8dec(yb0[rn]) + fp8dec(yb1[rn]) + fp8dec(yb2[rn])) * s_n * (1.f / 3.f);

  float ps = wave_sum(ue * pe);
  float ns = wave_sum(ue * ne);
  float x = ns - ps;
  float sp = fmaxf(x, 0.f) + log1pf(expf(-fabsf(x)));

  float eu = ut[(size_t)iu * DDIM + lane];
  float ep = it[(size_t)ip * DDIM + lane];
  float en = it[(size_t)ing * DDIM + lane];
  float rr = wave_sum(eu * eu + ep * ep + en * en);
  if (lane == 0) { sp_arr[b] = sp; rr_arr[b] = rr; }

  float n1 = fmaxf(sqrtf(wave_sum(cu * cu)), 1e-12f);
  float n2 = fmaxf(sqrtf(wave_sum(ue * ue)), 1e-12f);
  float d12 = wave_sum(cu * ue);
  z1u[(size_t)b * DDIM + lane] = f2bf(cu / n1);
  z2u[(size_t)b * DDIM + lane] = f2bf(ue / n2);
  if (lane == 0) pos_u[b] = d12 / (n1 * n2) * INV_TEMP;

  float m1 = fmaxf(sqrtf(wave_sum(ci * ci)), 1e-12f);
  float m2 = fmaxf(sqrtf(wave_sum(pe * pe)), 1e-12f);
  float e12 = wave_sum(ci * pe);
  z1i[(size_t)b * DDIM + lane] = f2bf(ci / m1);
  z2i[(size_t)b * DDIM + lane] = f2bf(pe / m2);
  if (lane == 0) pos_i[b] = e12 / (m1 * m2) * INV_TEMP;
}

// ---------------- InfoNCE via MFMA: one wave = 16x16 tile, K=64 ----------------------
__global__ __launch_bounds__(256) void infonce_kernel(const unsigned short* __restrict__ Z1,
                                                      const unsigned short* __restrict__ Z2,
                                                      float* __restrict__ rowpart) {
  __shared__ float part[16];
  int t = threadIdx.x;
  if (t < 16) part[t] = 0.f;
  __syncthreads();
  int wv = t >> 6, lane = t & 63;
  int i0 = blockIdx.y * 16;              // 16-row i-tile (shared by 4 waves)
  int j0 = blockIdx.x * 64 + wv * 16;    // each wave: its own 16-col group
  int m = lane & 15, q = lane >> 4;
  const unsigned short* ap = Z1 + (size_t)(i0 + m) * DDIM + q * 8;
  const unsigned short* bp = Z2 + (size_t)(j0 + m) * DDIM + q * 8;
  shortx8 a0 = *(const shortx8*)ap;
  shortx8 a1 = *(const shortx8*)(ap + 32);
  shortx8 b0 = *(const shortx8*)bp;
  shortx8 b1 = *(const shortx8*)(bp + 32);
  floatx4 acc = {0.f, 0.f, 0.f, 0.f};
  acc = __builtin_amdgcn_mfma_f32_16x16x32_bf16(a0, b0, acc, 0, 0, 0);
  acc = __builtin_amdgcn_mfma_f32_16x16x32_bf16(a1, b1, acc, 0, 0, 0);
  float s[4];
#pragma unroll
  for (int r = 0; r < 4; ++r) s[r] = __expf(acc[r] * INV_TEMP);
#pragma unroll
  for (int mm = 1; mm <= 8; mm <<= 1)
#pragma unroll
    for (int r = 0; r < 4; ++r) s[r] += __shfl_xor(s[r], mm, 64);
  if (m == 0) {
#pragma unroll
    for (int r = 0; r < 4; ++r) atomicAdd(&part[q * 4 + r], s[r]);
  }
  __syncthreads();
  if (t < 16) rowpart[(size_t)blockIdx.x * BB + i0 + t] = part[t];
}

// ---------------- reduce 64 partials per row into rowsum ----------------
__global__ __launch_bounds__(256) void reduce_kernel(const float* __restrict__ rowpart_u,
                                                     const float* __restrict__ rowpart_i,
                                                     float* __restrict__ rowsum_u,
                                                     float* __restrict__ rowsum_i) {
  int i = blockIdx.x * 256 + threadIdx.x;   // row index
  const float* src = blockIdx.y ? rowpart_i : rowpart_u;
  float s = 0.f;
#pragma unroll 8
  for (int jb = 0; jb < NJT; ++jb) s += __builtin_nontemporal_load(src + (size_t)jb * BB + i);
  if (blockIdx.y) rowsum_i[i] = s; else rowsum_u[i] = s;
}

// ---------------- finalize ----------------
__global__ __launch_bounds__(256) void finalize_kernel(const float* __restrict__ rowsum_u,
                                                       const float* __restrict__ pos_u,
                                                       const float* __restrict__ rowsum_i,
                                                       const float* __restrict__ pos_i,
                                                       const float* __restrict__ sp_arr,
                                                       const float* __restrict__ rr_arr,
                                                       float* __restrict__ out) {
  int t = threadIdx.x;
  float su = 0.f, si = 0.f, sb = 0.f, sr = 0.f;
  for (int i = t; i < BB; i += 256) {
    su += logf(rowsum_u[i]) - pos_u[i];
    si += logf(rowsum_i[i]) - pos_i[i];
    sb += sp_arr[i];
    sr += rr_arr[i];
  }
  su = wave_sum(su);
  si = wave_sum(si);
  sb = wave_sum(sb);
  sr = wave_sum(sr);
  __shared__ float sh[16];
  int lane = t & 63, wid = t >> 6;
  if (lane == 0) { sh[wid] = su; sh[4 + wid] = si; sh[8 + wid] = sb; sh[12 + wid] = sr; }
  __syncthreads();
  if (t == 0) {
    float SU = sh[0] + sh[1] + sh[2] + sh[3];
    float SI = sh[4] + sh[5] + sh[6] + sh[7];
    float SB = sh[8] + sh[9] + sh[10] + sh[11];
    float SR = sh[12] + sh[13] + sh[14] + sh[15];
    out[0] = SB * (1.f / BB);
    out[1] = 1e-4f * 0.5f * SR * (1.f / BB);
    out[2] = 0.2f * ((SU + SI) * (1.f / BB));
  }
}

extern "C" void kernel_launch(void* const* d_in, const int* in_sizes, int n_in,
                              void* d_out, int out_size, void* d_ws, size_t ws_size,
                              hipStream_t stream) {
  const float* user_table = (const float*)d_in[0];
  const float* item_table = (const float*)d_in[1];
  const float* noise      = (const float*)d_in[3];
  const int*   edge_src   = (const int*)d_in[4];
  const int*   edge_dst   = (const int*)d_in[5];
  const int*   user       = (const int*)d_in[6];
  const int*   positive   = (const int*)d_in[7];
  const int*   negative   = (const int*)d_in[8];
  const int E2 = in_sizes[2];  // 2,000,000

  const int eh = E2 >> 1;
  const int nbu = (eh + EPB - 1) / EPB;            // 245
  const int nbi = (E2 - eh + EPB - 1) / EPB;       // 245
  const int nbp = nbu + nbi;                       // 490

  char* w = (char*)d_ws;
  auto alloc = [&](size_t bytes) -> void* {
    void* p = (void*)w;
    w += (bytes + 255) & ~(size_t)255;
    return p;
  };
  int*   cbase    = (int*)alloc((size_t)NRANGE * 4);
  int*   rtot     = (int*)alloc((size_t)NRANGE * 4);
  int*   bcnt     = (int*)alloc((size_t)NRANGE * nbp * 4);
  int*   boff     = (int*)alloc((size_t)NRANGE * nbp * 4);
  int*   row_ptr  = (int*)alloc((size_t)(NNODE + 1) * 4);
  int*   counts   = (int*)alloc((size_t)NNODE * 4);
  int*   csr_dst  = (int*)alloc((size_t)E2 * 4);
  unsigned* binned = (unsigned*)alloc((size_t)E2 * 4);
  unsigned char* y_init = (unsigned char*)alloc((size_t)NNODE * DDIM);
  unsigned char* yb0    = (unsigned char*)alloc((size_t)NNODE * DDIM);
  unsigned char* yb1    = (unsigned char*)alloc((size_t)NNODE * DDIM);
  unsigned char* yb2    = (unsigned char*)alloc((size_t)NNODE * DDIM);
  unsigned short* z1u    = (unsigned short*)alloc((size_t)BB * DDIM * 2);
  unsigned short* z2u    = (unsigned short*)alloc((size_t)BB * DDIM * 2);
  unsigned short* z1i    = (unsigned short*)alloc((size_t)BB * DDIM * 2);
  unsigned short* z2i    = (unsigned short*)alloc((size_t)BB * DDIM * 2);
  float* pos_u    = (float*)alloc((size_t)BB * 4);
  float* pos_i    = (float*)alloc((size_t)BB * 4);
  float* rowsum_u = (float*)alloc((size_t)BB * 4);
  float* rowsum_i = (float*)alloc((size_t)BB * 4);
  float* sp_arr   = (float*)alloc((size_t)BB * 4);
  float* rr_arr   = (float*)alloc((size_t)BB * 4);
  float* rowpart_u = (float*)alloc((size_t)NJT * BB * 4);
  float* rowpart_i = (float*)alloc((size_t)NJT * BB * 4);

  pcount_kernel<<<nbp, 256, 0, stream>>>(edge_src, bcnt, E2, nbu, nbp);
  pscan_kernel<<<NRANGE, 256, 0, stream>>>(bcnt, boff, rtot, nbp);
  cscan2_kernel<<<1, 512, 0, stream>>>(rtot, cbase, row_ptr, E2);
  pscatter_kernel<<<nbp, 256, 0, stream>>>(edge_src, edge_dst, boff, cbase, binned,
                                           E2, nbu, nbp);
  place_kernel<<<NRANGE, 256, 0, stream>>>(binned, cbase, row_ptr, counts, csr_dst, E2);
  prescale_kernel<<<(NNODE * 16 + 255) / 256, 256, 0, stream>>>(user_table, item_table,
                                                                counts, y_init);
  const int spmm_blocks = (NNODE + 3) / 4;  // 4 waves per 256-thread block
  spmm_kernel<<<spmm_blocks, 256, 0, stream>>>(y_init, row_ptr, csr_dst, counts,
                                               noise + (size_t)0 * NNODE * DDIM, yb0);
  spmm_kernel<<<spmm_blocks, 256, 0, stream>>>(yb0, row_ptr, csr_dst, counts,
                                               noise + (size_t)1 * NNODE * DDIM, yb1);
  spmm_kernel<<<spmm_blocks, 256, 0, stream>>>(yb1, row_ptr, csr_dst, counts,
                                               noise + (size_t)2 * NNODE * DDIM, yb2);
  batch_kernel<<<BB / 4, 256, 0, stream>>>(yb0, yb1, yb2, user_table, item_table, counts,
                                           user, positive, negative,
                                           z1u, z2u, z1i, z2i, pos_u, pos_i, sp_arr, rr_arr);
  dim3 ig(NJT, BB / 16);
  infonce_kernel<<<ig, 256, 0, stream>>>(z1u, z2u, rowpart_u);
  infonce_kernel<<<ig, 256, 0, stream>>>(z1i, z2i, rowpart_i);
  dim3 rg(BB / 256, 2);
  reduce_kernel<<<rg, 256, 0, stream>>>(rowpart_u, rowpart_i, rowsum_u, rowsum_i);
  finalize_kernel<<<1, 256, 0, stream>>>(rowsum_u, pos_u, rowsum_i, pos_i,
                                         sp_arr, rr_arr, (float*)d_out);
}

// Round 15
// 420.749 us; speedup vs baseline: 2.5701x; 1.0228x over previous
//
#include <hip/hip_runtime.h>
#include <hip/hip_bf16.h>
#include <hip/hip_fp8.h>
#include <math.h>

#define UCNT 50000
#define ICNT 25000
#define NNODE 75000
#define DDIM 64
#define BB 4096
#define EPS_C 0.2f
#define INV_TEMP 5.0f
#define NJT (BB / 64)       // 64 j-tiles in infonce

#define NRANGE 293          // 256-node ranges
#define RB_U 196            // user-half ranges (0..195; range 195 shared w/ items)
#define RB_I 98             // item-half ranges (195..292 -> rel 0..97)
#define GOFF_I 195
#define EPB 4096            // edges per partition block (both halves)
#define YS 64.0f            // fp8 y scale (keeps elements in e4m3 normal range)
#define YSI (1.0f / 64.0f)

typedef float floatx4 __attribute__((ext_vector_type(4)));
typedef float floatx2 __attribute__((ext_vector_type(2)));
typedef unsigned short ushortx4 __attribute__((ext_vector_type(4)));
typedef short shortx8 __attribute__((ext_vector_type(8)));

__device__ __forceinline__ float wave_sum(float x) {
#pragma unroll
  for (int m = 32; m >= 1; m >>= 1) x += __shfl_xor(x, m, 64);
  return x;
}

__device__ __forceinline__ unsigned short f2bf(float f) {   // RNE
  unsigned u = __float_as_uint(f);
  u += 0x7fffu + ((u >> 16) & 1u);
  return (unsigned short)(u >> 16);
}
__device__ __forceinline__ unsigned char fp8enc(float f) {
  __hip_fp8_e4m3 h(f); return h.__x;
}
__device__ __forceinline__ float fp8dec1(unsigned char b) {
  __hip_fp8_e4m3 h; h.__x = b; return (float)h;
}

// ---------------- pcount: per (stripe-block, range) histogram -> bcnt column ---------
__global__ __launch_bounds__(256) void pcount_kernel(const int* __restrict__ src,
                                                     int* __restrict__ bcnt,
                                                     int ne, int nbu, int nbp) {
  __shared__ int qc[RB_U];
  int t = threadIdx.x;
  int b = blockIdx.x;
  int eh = ne >> 1;
  bool isU = b < nbu;
  int base = isU ? b * EPB : eh + (b - nbu) * EPB;
  int lim = min(base + EPB, isU ? eh : ne);
  int RB = isU ? RB_U : RB_I;
  int goff = isU ? 0 : GOFF_I;
  for (int i = t; i < RB; i += 256) qc[i] = 0;
  __syncthreads();
  for (int i = base + t; i < lim; i += 256) {
    int s = __builtin_nontemporal_load(src + i);
    atomicAdd(&qc[(s >> 8) - goff], 1);
  }
  __syncthreads();
  for (int r = t; r < NRANGE; r += 256) {
    int rel = r - goff;
    int v = (rel >= 0 && rel < RB) ? qc[rel] : 0;
    bcnt[(size_t)r * nbp + b] = v;
  }
}

// ---------------- pscan: per range, local exclusive scan over block columns ----------
__global__ __launch_bounds__(256) void pscan_kernel(const int* __restrict__ bcnt,
                                                    int* __restrict__ boff,
                                                    int* __restrict__ rtot, int nbp) {
  __shared__ int s0[512], s1[512];
  int r = blockIdx.x, t = threadIdx.x;
  for (int j = t; j < 512; j += 256) s0[j] = (j < nbp) ? bcnt[(size_t)r * nbp + j] : 0;
  __syncthreads();
  int* a = s0;
  int* bf = s1;
  for (int off = 1; off < 512; off <<= 1) {
    for (int j = t; j < 512; j += 256) bf[j] = a[j] + ((j >= off) ? a[j - off] : 0);
    __syncthreads();
    int* tmp = a; a = bf; bf = tmp;
  }
  for (int j = t; j < nbp; j += 256)
    boff[(size_t)r * nbp + j] = a[j] - bcnt[(size_t)r * nbp + j];
  if (t == 0) rtot[r] = a[511];
}

// ---------------- cscan2: scan 293 range totals -> cbase ----------------
__global__ __launch_bounds__(512) void cscan2_kernel(const int* __restrict__ rtot,
                                                     int* __restrict__ cbase,
                                                     int* __restrict__ row_ptr, int ne) {
  int t = threadIdx.x;
  int lane = t & 63, wid = t >> 6;
  int c = (t < NRANGE) ? rtot[t] : 0;
  int v = c;
#pragma unroll
  for (int d = 1; d < 64; d <<= 1) {
    int u = __shfl_up(v, d, 64);
    if (lane >= d) v += u;
  }
  __shared__ int ws[8], wo[8];
  if (lane == 63) ws[wid] = v;
  __syncthreads();
  if (t == 0) {
    int run = 0;
    for (int k = 0; k < 8; ++k) { wo[k] = run; run += ws[k]; }
    row_ptr[NNODE] = ne;
  }
  __syncthreads();
  if (t < NRANGE) cbase[t] = v - c + wo[wid];
}

// ---------------- pscatter: deterministic binning into u32 (srcLow8 | dst) -----------
__global__ __launch_bounds__(256) void pscatter_kernel(const int* __restrict__ src,
                                                       const int* __restrict__ dst,
                                                       const int* __restrict__ boff,
                                                       const int* __restrict__ cbase,
                                                       unsigned* __restrict__ binned,
                                                       int ne, int nbu, int nbp) {
  __shared__ int qc[RB_U];
  int t = threadIdx.x;
  int b = blockIdx.x;
  int eh = ne >> 1;
  bool isU = b < nbu;
  int base = isU ? b * EPB : eh + (b - nbu) * EPB;
  int lim = min(base + EPB, isU ? eh : ne);
  int goff = isU ? 0 : GOFF_I;
  int RB = isU ? RB_U : RB_I;
  for (int i = t; i < RB; i += 256) qc[i] = 0;
  __syncthreads();
  for (int i = base + t; i < lim; i += 256) {
    int s = __builtin_nontemporal_load(src + i);
    int d = __builtin_nontemporal_load(dst + i);
    int rb = (s >> 8) - goff;
    int pos = atomicAdd(&qc[rb], 1);
    int rg = rb + goff;
    int g = cbase[rg] + boff[(size_t)rg * nbp + b] + pos;
    binned[g] = ((unsigned)(s & 255) << 24) | (unsigned)d;   // dst < 2^24
  }
}

// ---------------- place: one block per range -> row_ptr, counts, csr (private region)
__global__ __launch_bounds__(256) void place_kernel(
    const unsigned* __restrict__ binned, const int* __restrict__ cbase,
    int* __restrict__ row_ptr, int* __restrict__ counts,
    int* __restrict__ csr_dst, int ne) {
  __shared__ int cnt[256], cur[256], ws[4], wo[4];
  int t = threadIdx.x;
  int b = blockIdx.x;
  int r0 = b << 8;
  int seg0 = cbase[b];
  int seg1 = (b == NRANGE - 1) ? ne : cbase[b + 1];
  cnt[t] = 0;
  __syncthreads();
  for (int j = seg0 + t; j < seg1; j += 256)
    atomicAdd(&cnt[binned[j] >> 24], 1);
  __syncthreads();
  int c = cnt[t];
  int lane = t & 63, wid = t >> 6;
  int v = c;
#pragma unroll
  for (int d = 1; d < 64; d <<= 1) {
    int u = __shfl_up(v, d, 64);
    if (lane >= d) v += u;
  }
  if (lane == 63) ws[wid] = v;
  __syncthreads();
  if (t == 0) {
    int run = 0;
    for (int k = 0; k < 4; ++k) { wo[k] = run; run += ws[k]; }
  }
  __syncthreads();
  int excl = v - c + wo[wid];
  if (r0 + t < NNODE) {
    row_ptr[r0 + t] = seg0 + excl;
    counts[r0 + t] = c;
  }
  cur[t] = excl;
  __syncthreads();
  for (int j = seg0 + t; j < seg1; j += 256) {
    unsigned e = binned[j];
    int off = atomicAdd(&cur[e >> 24], 1);
    csr_dst[seg0 + off] = (int)(e & 0xFFFFFFu);
  }
}

// ---------------- prescale: y_init[n] = fp8(table[n] * rsqrt(max(deg,1)) * YS) -------
__global__ __launch_bounds__(256) void prescale_kernel(const float* __restrict__ ut,
                                                       const float* __restrict__ it,
                                                       const int* __restrict__ counts,
                                                       unsigned char* __restrict__ y) {
  int idx = blockIdx.x * 256 + threadIdx.x;   // one 4-dim group per thread
  if (idx >= NNODE * 16) return;
  int n = idx >> 4;
  float sc = rsqrtf(fmaxf((float)counts[n], 1.f)) * YS;
  const float* srcp = (n < UCNT) ? (ut + (size_t)n * DDIM)
                                 : (it + (size_t)(n - UCNT) * DDIM);
  float4 v = *(const float4*)(srcp + (idx & 15) * 4);
  uchar4 o;
  o.x = fp8enc(v.x * sc); o.y = fp8enc(v.y * sc);
  o.z = fp8enc(v.z * sc); o.w = fp8enc(v.w * sc);
  *(uchar4*)(y + (size_t)idx * 4) = o;
}

// ---------------- SpMM over fp8 rows: packed HW decode, branch-free main loop --------
__global__ __launch_bounds__(256) void spmm_kernel(const unsigned char* __restrict__ y_in,
                                                   const int* __restrict__ row_ptr,
                                                   const int* __restrict__ csr_dst,
                                                   const int* __restrict__ counts,
                                                   const float* __restrict__ noise,
                                                   unsigned char* __restrict__ y_out) {
  int wave = blockIdx.x * 4 + (threadIdx.x >> 6);
  int lane = threadIdx.x & 63;
  if (wave >= NNODE) return;
  int r = wave;
  int beg = row_ptr[r], endp = row_ptr[r + 1];
  int g = lane >> 3, l8 = lane & 7;   // 8 edge-subgroups x 8 dim-slices (8 dims each)
  floatx2 a0 = {0.f, 0.f}, a1 = {0.f, 0.f}, a2 = {0.f, 0.f}, a3 = {0.f, 0.f};
  int e0 = beg;
  for (; e0 + 64 <= endp; e0 += 64) {          // branch-free full chunks
    int d = __builtin_nontemporal_load(csr_dst + e0 + lane);
#pragma unroll
    for (int j = 0; j < 64; j += 8) {
      int dj = __shfl(d, j + g, 64);
      uint2 pk = *(const uint2*)(y_in + (size_t)dj * DDIM + l8 * 8);
      a0 += __builtin_amdgcn_cvt_pk_f32_fp8(pk.x, 0);
      a1 += __builtin_amdgcn_cvt_pk_f32_fp8(pk.x, 1);
      a2 += __builtin_amdgcn_cvt_pk_f32_fp8(pk.y, 0);
      a3 += __builtin_amdgcn_cvt_pk_f32_fp8(pk.y, 1);
    }
  }
  if (e0 < endp) {                             // tail chunk
    int e = e0 + lane;
    int d = (e < endp) ? __builtin_nontemporal_load(csr_dst + e) : 0;
    int cnt = endp - e0;
    for (int j = 0; j < cnt; j += 8) {
      int dj = __shfl(d, j + g, 64);
      if (j + g < cnt) {
        uint2 pk = *(const uint2*)(y_in + (size_t)dj * DDIM + l8 * 8);
        a0 += __builtin_amdgcn_cvt_pk_f32_fp8(pk.x, 0);
        a1 += __builtin_amdgcn_cvt_pk_f32_fp8(pk.x, 1);
        a2 += __builtin_amdgcn_cvt_pk_f32_fp8(pk.y, 0);
        a3 += __builtin_amdgcn_cvt_pk_f32_fp8(pk.y, 1);
      }
    }
  }
  float acc[8] = {a0[0], a0[1], a1[0], a1[1], a2[0], a2[1], a3[0], a3[1]};
#pragma unroll
  for (int m = 8; m <= 32; m <<= 1)
#pragma unroll
    for (int k = 0; k < 8; ++k) acc[k] += __shfl_xor(acc[k], m, 64);
  float sc = rsqrtf(fmaxf((float)counts[r], 1.f));
  floatx4 n0 = __builtin_nontemporal_load((const floatx4*)(noise + (size_t)r * DDIM + l8 * 8));
  floatx4 n1 = __builtin_nontemporal_load((const floatx4*)(noise + (size_t)r * DDIM + l8 * 8 + 4));
  float nf[8] = {n0[0], n0[1], n0[2], n0[3], n1[0], n1[1], n1[2], n1[3]};
  float ss = 0.f;
#pragma unroll
  for (int k = 0; k < 8; ++k) ss += nf[k] * nf[k];
#pragma unroll
  for (int m = 1; m <= 4; m <<= 1) ss += __shfl_xor(ss, m, 64);   // within 8-lane slice group
  float inv = EPS_C / fmaxf(sqrtf(ss), 1e-12f);
  if (g == 0) {
    unsigned char ov[8];
#pragma unroll
    for (int k = 0; k < 8; ++k) {
      float x = acc[k] * sc * YSI;           // undo fp8 scale from gathered terms
      float sgn = (x > 0.f) ? 1.f : ((x < 0.f) ? -1.f : 0.f);
      ov[k] = fp8enc((x + sgn * nf[k] * inv) * sc * YS);   // store y = x_out * sc (scaled)
    }
    *(uint2*)(y_out + (size_t)r * DDIM + l8 * 8) = *(uint2*)ov;
  }
}

// ---------------- batch gather: BPR, reg, bf16 normalized InfoNCE inputs -------------
__global__ __launch_bounds__(256) void batch_kernel(
    const unsigned char* __restrict__ yb0, const unsigned char* __restrict__ yb1,
    const unsigned char* __restrict__ yb2,
    const float* __restrict__ ut, const float* __restrict__ it,
    const int* __restrict__ counts,
    const int* __restrict__ user, const int* __restrict__ pos, const int* __restrict__ neg,
    unsigned short* __restrict__ z1u, unsigned short* __restrict__ z2u,
    unsigned short* __restrict__ z1i, unsigned short* __restrict__ z2i,
    float* __restrict__ pos_u, float* __restrict__ pos_i,
    float* __restrict__ sp_arr, float* __restrict__ rr_arr) {
  int wave = blockIdx.x * (blockDim.x >> 6) + (threadIdx.x >> 6);
  int lane = threadIdx.x & 63;
  if (wave >= BB) return;
  int b = wave;
  int iu = user[b], ip = pos[b], ing = neg[b];
  float s_u = sqrtf(fmaxf((float)counts[iu], 1.f)) * YSI;
  float s_p = sqrtf(fmaxf((float)counts[UCNT + ip], 1.f)) * YSI;
  float s_n = sqrtf(fmaxf((float)counts[UCNT + ing], 1.f)) * YSI;
  size_t ru = (size_t)iu * DDIM + lane;
  size_t rp = (size_t)(UCNT + ip) * DDIM + lane;
  size_t rn = (size_t)(UCNT + ing) * DDIM + lane;
  float cu = fp8dec1(yb0[ru]) * s_u;        // x_cl user row
  float ci = fp8dec1(yb0[rp]) * s_p;        // x_cl positive-item row
  float ue = (cu + (fp8dec1(yb1[ru]) + fp8dec1(yb2[ru])) * s_u) * (1.f / 3.f);
  float pe = (ci + (fp8dec1(yb1[rp]) + fp8dec1(yb2[rp])) * s_p) * (1.f / 3.f);
  float ne = (fp8dec1(yb0[rn]) + fp8dec1(yb1[rn]) + fp8dec1(yb2[rn])) * s_n * (1.f / 3.f);

  float ps = wave_sum(ue * pe);
  float ns = wave_sum(ue * ne);
  float x = ns - ps;
  float sp = fmaxf(x, 0.f) + log1pf(expf(-fabsf(x)));

  float eu = ut[(size_t)iu * DDIM + lane];
  float ep = it[(size_t)ip * DDIM + lane];
  float en = it[(size_t)ing * DDIM + lane];
  float rr = wave_sum(eu * eu + ep * ep + en * en);
  if (lane == 0) { sp_arr[b] = sp; rr_arr[b] = rr; }

  float n1 = fmaxf(sqrtf(wave_sum(cu * cu)), 1e-12f);
  float n2 = fmaxf(sqrtf(wave_sum(ue * ue)), 1e-12f);
  float d12 = wave_sum(cu * ue);
  z1u[(size_t)b * DDIM + lane] = f2bf(cu / n1);
  z2u[(size_t)b * DDIM + lane] = f2bf(ue / n2);
  if (lane == 0) pos_u[b] = d12 / (n1 * n2) * INV_TEMP;

  float m1 = fmaxf(sqrtf(wave_sum(ci * ci)), 1e-12f);
  float m2 = fmaxf(sqrtf(wave_sum(pe * pe)), 1e-12f);
  float e12 = wave_sum(ci * pe);
  z1i[(size_t)b * DDIM + lane] = f2bf(ci / m1);
  z2i[(size_t)b * DDIM + lane] = f2bf(pe / m2);
  if (lane == 0) pos_i[b] = e12 / (m1 * m2) * INV_TEMP;
}

// ---------------- InfoNCE via MFMA: one wave = 16x16 tile, K=64 ----------------------
__global__ __launch_bounds__(256) void infonce_kernel(const unsigned short* __restrict__ Z1,
                                                      const unsigned short* __restrict__ Z2,
                                                      float* __restrict__ rowpart) {
  __shared__ float part[16];
  int t = threadIdx.x;
  if (t < 16) part[t] = 0.f;
  __syncthreads();
  int wv = t >> 6, lane = t & 63;
  int i0 = blockIdx.y * 16;              // 16-row i-tile (shared by 4 waves)
  int j0 = blockIdx.x * 64 + wv * 16;    // each wave: its own 16-col group
  int m = lane & 15, q = lane >> 4;
  const unsigned short* ap = Z1 + (size_t)(i0 + m) * DDIM + q * 8;
  const unsigned short* bp = Z2 + (size_t)(j0 + m) * DDIM + q * 8;
  shortx8 a0 = *(const shortx8*)ap;
  shortx8 a1 = *(const shortx8*)(ap + 32);
  shortx8 b0 = *(const shortx8*)bp;
  shortx8 b1 = *(const shortx8*)(bp + 32);
  floatx4 acc = {0.f, 0.f, 0.f, 0.f};
  acc = __builtin_amdgcn_mfma_f32_16x16x32_bf16(a0, b0, acc, 0, 0, 0);
  acc = __builtin_amdgcn_mfma_f32_16x16x32_bf16(a1, b1, acc, 0, 0, 0);
  float s[4];
#pragma unroll
  for (int r = 0; r < 4; ++r) s[r] = __expf(acc[r] * INV_TEMP);
#pragma unroll
  for (int mm = 1; mm <= 8; mm <<= 1)
#pragma unroll
    for (int r = 0; r < 4; ++r) s[r] += __shfl_xor(s[r], mm, 64);
  if (m == 0) {
#pragma unroll
    for (int r = 0; r < 4; ++r) atomicAdd(&part[q * 4 + r], s[r]);
  }
  __syncthreads();
  if (t < 16) rowpart[(size_t)blockIdx.x * BB + i0 + t] = part[t];
}

// ---------------- reduce 64 partials per row into rowsum ----------------
__global__ __launch_bounds__(256) void reduce_kernel(const float* __restrict__ rowpart_u,
                                                     const float* __restrict__ rowpart_i,
                                                     float* __restrict__ rowsum_u,
                                                     float* __restrict__ rowsum_i) {
  int i = blockIdx.x * 256 + threadIdx.x;   // row index
  const float* src = blockIdx.y ? rowpart_i : rowpart_u;
  float s = 0.f;
#pragma unroll 8
  for (int jb = 0; jb < NJT; ++jb) s += __builtin_nontemporal_load(src + (size_t)jb * BB + i);
  if (blockIdx.y) rowsum_i[i] = s; else rowsum_u[i] = s;
}

// ---------------- finalize ----------------
__global__ __launch_bounds__(256) void finalize_kernel(const float* __restrict__ rowsum_u,
                                                       const float* __restrict__ pos_u,
                                                       const float* __restrict__ rowsum_i,
                                                       const float* __restrict__ pos_i,
                                                       const float* __restrict__ sp_arr,
                                                       const float* __restrict__ rr_arr,
                                                       float* __restrict__ out) {
  int t = threadIdx.x;
  float su = 0.f, si = 0.f, sb = 0.f, sr = 0.f;
  for (int i = t; i < BB; i += 256) {
    su += logf(rowsum_u[i]) - pos_u[i];
    si += logf(rowsum_i[i]) - pos_i[i];
    sb += sp_arr[i];
    sr += rr_arr[i];
  }
  su = wave_sum(su);
  si = wave_sum(si);
  sb = wave_sum(sb);
  sr = wave_sum(sr);
  __shared__ float sh[16];
  int lane = t & 63, wid = t >> 6;
  if (lane == 0) { sh[wid] = su; sh[4 + wid] = si; sh[8 + wid] = sb; sh[12 + wid] = sr; }
  __syncthreads();
  if (t == 0) {
    float SU = sh[0] + sh[1] + sh[2] + sh[3];
    float SI = sh[4] + sh[5] + sh[6] + sh[7];
    float SB = sh[8] + sh[9] + sh[10] + sh[11];
    float SR = sh[12] + sh[13] + sh[14] + sh[15];
    out[0] = SB * (1.f / BB);
    out[1] = 1e-4f * 0.5f * SR * (1.f / BB);
    out[2] = 0.2f * ((SU + SI) * (1.f / BB));
  }
}

extern "C" void kernel_launch(void* const* d_in, const int* in_sizes, int n_in,
                              void* d_out, int out_size, void* d_ws, size_t ws_size,
                              hipStream_t stream) {
  const float* user_table = (const float*)d_in[0];
  const float* item_table = (const float*)d_in[1];
  const float* noise      = (const float*)d_in[3];
  const int*   edge_src   = (const int*)d_in[4];
  const int*   edge_dst   = (const int*)d_in[5];
  const int*   user       = (const int*)d_in[6];
  const int*   positive   = (const int*)d_in[7];
  const int*   negative   = (const int*)d_in[8];
  const int E2 = in_sizes[2];  // 2,000,000

  const int eh = E2 >> 1;
  const int nbu = (eh + EPB - 1) / EPB;            // 245
  const int nbi = (E2 - eh + EPB - 1) / EPB;       // 245
  const int nbp = nbu + nbi;                       // 490

  char* w = (char*)d_ws;
  auto alloc = [&](size_t bytes) -> void* {
    void* p = (void*)w;
    w += (bytes + 255) & ~(size_t)255;
    return p;
  };
  int*   cbase    = (int*)alloc((size_t)NRANGE * 4);
  int*   rtot     = (int*)alloc((size_t)NRANGE * 4);
  int*   bcnt     = (int*)alloc((size_t)NRANGE * nbp * 4);
  int*   boff     = (int*)alloc((size_t)NRANGE * nbp * 4);
  int*   row_ptr  = (int*)alloc((size_t)(NNODE + 1) * 4);
  int*   counts   = (int*)alloc((size_t)NNODE * 4);
  int*   csr_dst  = (int*)alloc((size_t)E2 * 4);
  unsigned* binned = (unsigned*)alloc((size_t)E2 * 4);
  unsigned char* y_init = (unsigned char*)alloc((size_t)NNODE * DDIM);
  unsigned char* yb0    = (unsigned char*)alloc((size_t)NNODE * DDIM);
  unsigned char* yb1    = (unsigned char*)alloc((size_t)NNODE * DDIM);
  unsigned char* yb2    = (unsigned char*)alloc((size_t)NNODE * DDIM);
  unsigned short* z1u    = (unsigned short*)alloc((size_t)BB * DDIM * 2);
  unsigned short* z2u    = (unsigned short*)alloc((size_t)BB * DDIM * 2);
  unsigned short* z1i    = (unsigned short*)alloc((size_t)BB * DDIM * 2);
  unsigned short* z2i    = (unsigned short*)alloc((size_t)BB * DDIM * 2);
  float* pos_u    = (float*)alloc((size_t)BB * 4);
  float* pos_i    = (float*)alloc((size_t)BB * 4);
  float* rowsum_u = (float*)alloc((size_t)BB * 4);
  float* rowsum_i = (float*)alloc((size_t)BB * 4);
  float* sp_arr   = (float*)alloc((size_t)BB * 4);
  float* rr_arr   = (float*)alloc((size_t)BB * 4);
  float* rowpart_u = (float*)alloc((size_t)NJT * BB * 4);
  float* rowpart_i = (float*)alloc((size_t)NJT * BB * 4);

  pcount_kernel<<<nbp, 256, 0, stream>>>(edge_src, bcnt, E2, nbu, nbp);
  pscan_kernel<<<NRANGE, 256, 0, stream>>>(bcnt, boff, rtot, nbp);
  cscan2_kernel<<<1, 512, 0, stream>>>(rtot, cbase, row_ptr, E2);
  pscatter_kernel<<<nbp, 256, 0, stream>>>(edge_src, edge_dst, boff, cbase, binned,
                                           E2, nbu, nbp);
  place_kernel<<<NRANGE, 256, 0, stream>>>(binned, cbase, row_ptr, counts, csr_dst, E2);
  prescale_kernel<<<(NNODE * 16 + 255) / 256, 256, 0, stream>>>(user_table, item_table,
                                                                counts, y_init);
  const int spmm_blocks = (NNODE + 3) / 4;  // 4 waves per 256-thread block
  spmm_kernel<<<spmm_blocks, 256, 0, stream>>>(y_init, row_ptr, csr_dst, counts,
                                               noise + (size_t)0 * NNODE * DDIM, yb0);
  spmm_kernel<<<spmm_blocks, 256, 0, stream>>>(yb0, row_ptr, csr_dst, counts,
                                               noise + (size_t)1 * NNODE * DDIM, yb1);
  spmm_kernel<<<spmm_blocks, 256, 0, stream>>>(yb1, row_ptr, csr_dst, counts,
                                               noise + (size_t)2 * NNODE * DDIM, yb2);
  batch_kernel<<<BB / 4, 256, 0, stream>>>(yb0, yb1, yb2, user_table, item_table, counts,
                                           user, positive, negative,
                                           z1u, z2u, z1i, z2i, pos_u, pos_i, sp_arr, rr_arr);
  dim3 ig(NJT, BB / 16);
  infonce_kernel<<<ig, 256, 0, stream>>>(z1u, z2u, rowpart_u);
  infonce_kernel<<<ig, 256, 0, stream>>>(z1i, z2i, rowpart_i);
  dim3 rg(BB / 256, 2);
  reduce_kernel<<<rg, 256, 0, stream>>>(rowpart_u, rowpart_i, rowsum_u, rowsum_i);
  finalize_kernel<<<1, 256, 0, stream>>>(rowsum_u, pos_u, rowsum_i, pos_i,
                                         sp_arr, rr_arr, (float*)d_out);
}